// Round 2
// baseline (470.973 us; speedup 1.0000x reference)
//
#include <hip/hip_runtime.h>
#include <stdint.h>

// ---------------------------------------------------------------------------
// Gemma4 MoE block on gfx950. FP16 MFMA (16x16x32) GEMMs, f32 accumulation.
// R2: sparse top-2 routed experts (tile-padded bucketing + grouped GEMMs).
// R4: gated dual-GEMM, XOR source swizzle. R6: dispatch merging (10 launches).
// R7: pipelined GEMMs — 512 thr / 8 waves, tile 128x256, BK=32, double-
//     buffered LDS, counted vmcnt, raw s_barrier, setprio. REGRESSED: C++ LDS
//     reads made the backend insert vmcnt(0) drains (alias safety).
// R8: fragment loads via volatile inline-asm ds_read_b128 (invisible to alias
//     analysis) + lgkmcnt(0) + sched_barrier(0) (rule #18). Counted vmcnt now
//     real: one tile stays in flight across both barriers.
// ---------------------------------------------------------------------------

typedef unsigned short u16;
typedef u16 u16x4 __attribute__((ext_vector_type(4)));
typedef u16 u16x8 __attribute__((ext_vector_type(8)));
typedef _Float16 f16x8 __attribute__((ext_vector_type(8)));
typedef float f32x4 __attribute__((ext_vector_type(4)));
typedef __attribute__((address_space(1))) void* as1_vp;
typedef __attribute__((address_space(3))) void* as3_vp;

#define T_TOK 4096
#define DIM   1024
#define FDIM  2048
#define MDIM  1024
#define NEXP  8
#define MAXTILES 72            // sum ceil(cnt_e/128) <= 64 + 7, padded
#define HROWS (MAXTILES * 128) // 9216 padded assignment rows

__device__ __forceinline__ u16 f2h(float f) {
  _Float16 h = (_Float16)f;
  return __builtin_bit_cast(u16, h);
}
__device__ __forceinline__ float h2f(u16 u) {
  return (float)__builtin_bit_cast(_Float16, u);
}
// tanh-approx gelu rewritten exactly as x*sigmoid(2y): cheap __expf + div
__device__ __forceinline__ float gelu_f(float x) {
  const float y2 = x * (1.5957691216f + 0.0713548163f * x * x);
  return x / (1.0f + __expf(-y2));
}
__device__ __forceinline__ void async_copy16(const void* g, void* l) {
  __builtin_amdgcn_global_load_lds((as1_vp)(uintptr_t)g,
                                   (as3_vp)(uint32_t)(uintptr_t)l, 16, 0, 0);
}
// Volatile asm ds_read_b128: invisible to the backend's LDS alias analysis,
// so no compiler-inserted vmcnt(0) drain before fragment reads. Completion
// is enforced by explicit s_waitcnt lgkmcnt(0) + sched_barrier(0).
__device__ __forceinline__ f16x8 ds_read128(const u16* p) {
  f16x8 r;
  asm volatile("ds_read_b128 %0, %1"
               : "=v"(r)
               : "v"((uint32_t)(uintptr_t)p));
  return r;
}

// ---------------------------------------------------------------------------
// Merged gated dual-GEMM (shared + routed in ONE dispatch), pipelined.
// H = gelu(A@B0) * (A@B1), f16. 512 thr / 8 waves (2x4 of 64x64), dual acc.
// Tile 128x256, BK=32, LDS 80 KB (2x(8+16+16)), 2-deep prefetch pipeline.
// blockIdx.y < 32: shared (A=x_sh, N=FDIM). y>=32: routed tile (gather,
// N=MDIM, x < 4). K = DIM = 1024 for both.
// ---------------------------------------------------------------------------
__global__ __launch_bounds__(512, 2) void gemm_in(
    const u16* __restrict__ xs, const u16* __restrict__ swi_t,
    const u16* __restrict__ routed, const u16* __restrict__ ewi_t,
    u16* __restrict__ Hs, u16* __restrict__ Hr,
    const int* __restrict__ ridx, const int2* __restrict__ tdesc,
    const int* __restrict__ n_tiles) {
  const int yb = (int)blockIdx.y;
  const u16 *A, *B0t, *B1t;
  u16* H;
  int N;
  long bm;
  bool gather;
  if (yb < 32) {
    bm = (long)yb * 128;
    A = xs;
    B0t = swi_t;
    B1t = swi_t + (size_t)FDIM * DIM;
    H = Hs;
    N = FDIM;
    gather = false;
  } else {
    const int ty = yb - 32;
    if (ty >= *n_tiles) return;
    if ((int)blockIdx.x >= MDIM / 256) return;
    const int2 td = tdesc[ty];
    bm = td.y;
    A = routed;
    B0t = ewi_t + (long)td.x * MDIM * DIM;
    B1t = ewi_t + (size_t)NEXP * MDIM * DIM + (long)td.x * MDIM * DIM;
    H = Hr;
    N = MDIM;
    gather = true;
  }
  __shared__ __align__(16) u16 As[2][128 * 32];   // 16 KB
  __shared__ __align__(16) u16 Bs0[2][256 * 32];  // 32 KB
  __shared__ __align__(16) u16 Bs1[2][256 * 32];  // 32 KB
  const int tid = threadIdx.x;
  const int lane = tid & 63;
  const int wave = tid >> 6;        // 0..7
  const int wm = (wave >> 2) * 64;  // 0,64
  const int wn = (wave & 3) * 64;   // 0,64,128,192
  const long bn = (long)blockIdx.x * 256;

  f32x4 acc0[4][4] = {}, acc1[4][4] = {};

  // Staging: 1 A-chunk + 2 B0-chunks + 2 B1-chunks (16B each) per thread per
  // K-tile. LDS dest lane-linear (slot = chunk id); swizzle applied on the
  // global SOURCE k-offset: chunk c of row r holds k-group c ^ ((r>>1)&3).
  const int r0 = tid >> 2;
  const int cs = ((tid & 3) ^ ((r0 >> 1) & 3)) * 8;
  const u16* Asrc = (gather ? A + (long)ridx[bm + r0] * DIM
                            : A + (bm + r0) * (long)DIM) + cs;
  const u16* B0a = B0t + (bn + r0) * (long)DIM + cs;
  const u16* B0b = B0t + (bn + r0 + 128) * (long)DIM + cs;
  const u16* B1a = B1t + (bn + r0) * (long)DIM + cs;
  const u16* B1b = B1t + (bn + r0 + 128) * (long)DIM + cs;
  const int fr = lane & 15;
  const int fq = lane >> 4;
  const int qs = (fq ^ ((fr >> 1) & 3)) * 8;  // swizzled k-chunk offset (u16)

#define STAGE_IN(buf, kt)                                  \
  {                                                        \
    const int k0_ = (kt) * 32;                             \
    async_copy16(Asrc + k0_, &As[buf][tid * 8]);           \
    async_copy16(B0a + k0_, &Bs0[buf][tid * 8]);           \
    async_copy16(B0b + k0_, &Bs0[buf][(tid + 512) * 8]);   \
    async_copy16(B1a + k0_, &Bs1[buf][tid * 8]);           \
    async_copy16(B1b + k0_, &Bs1[buf][(tid + 512) * 8]);   \
  }

  const int NT = DIM / 32;  // 32 K-tiles
  STAGE_IN(0, 0);
  STAGE_IN(1, 1);
  int cur = 0;
  for (int t = 0; t < NT; ++t) {
    // tile t landed; tile t+1's 5 loads stay in flight across both barriers
    if (t + 2 < NT) {
      asm volatile("s_waitcnt vmcnt(5)" ::: "memory");
    } else {
      asm volatile("s_waitcnt vmcnt(0)" ::: "memory");
    }
    __builtin_amdgcn_s_barrier();
    f16x8 af[4], b0f[4], b1f[4];
    {
      const u16* Ap = &As[cur][0];
      const u16* B0p = &Bs0[cur][0];
      const u16* B1p = &Bs1[cur][0];
#pragma unroll
      for (int i = 0; i < 4; i++) {
        af[i]  = ds_read128(Ap  + (wm + i * 16 + fr) * 32 + qs);
        b0f[i] = ds_read128(B0p + (wn + i * 16 + fr) * 32 + qs);
        b1f[i] = ds_read128(B1p + (wn + i * 16 + fr) * 32 + qs);
      }
    }
    asm volatile("s_waitcnt lgkmcnt(0)" ::: "memory");
    __builtin_amdgcn_sched_barrier(0);
    __builtin_amdgcn_s_barrier();  // all waves done reading buf[cur]
    if (t + 2 < NT) STAGE_IN(cur, t + 2);  // overwrite-safe after barrier
    __builtin_amdgcn_s_setprio(1);
#pragma unroll
    for (int mi = 0; mi < 4; mi++)
#pragma unroll
      for (int ni = 0; ni < 4; ni++) {
        acc0[mi][ni] = __builtin_amdgcn_mfma_f32_16x16x32_f16(af[mi], b0f[ni], acc0[mi][ni], 0, 0, 0);
        acc1[mi][ni] = __builtin_amdgcn_mfma_f32_16x16x32_f16(af[mi], b1f[ni], acc1[mi][ni], 0, 0, 0);
      }
    __builtin_amdgcn_s_setprio(0);
    cur ^= 1;
  }
#undef STAGE_IN

  const int er = (lane >> 4) * 4;  // C/D: col=lane&15, row=(lane>>4)*4+reg
  const int ec = lane & 15;
#pragma unroll
  for (int mi = 0; mi < 4; mi++)
#pragma unroll
    for (int r = 0; r < 4; r++) {
      const long row = bm + wm + mi * 16 + er + r;
#pragma unroll
      for (int ni = 0; ni < 4; ni++)
        H[row * N + bn + wn + ni * 16 + ec] =
            f2h(gelu_f(acc0[mi][ni][r]) * acc1[mi][ni][r]);
    }
}

// ---------------------------------------------------------------------------
// Merged out-GEMM (shared + routed, split-K via grid.z), pipelined.
// 512 thr / 8 waves, tile 128x256, BK=32, LDS 48 KB, 2-deep prefetch.
// y<32: shared A=Hs (Kfull=FDIM), C=racc partials.
// y>=32: routed tile (padded positions, Kfull=MDIM), C=Hout partials.
// N = DIM for both; x < 4.
// ---------------------------------------------------------------------------
__global__ __launch_bounds__(512, 2) void gemm_out2(
    const u16* __restrict__ Hs, const u16* __restrict__ swo_t,
    float* __restrict__ racc, const u16* __restrict__ Hr,
    const u16* __restrict__ ewo_t, float* __restrict__ Hout,
    const int2* __restrict__ tdesc, const int* __restrict__ n_tiles) {
  const int yb = (int)blockIdx.y;
  const u16 *A, *Bt;
  float* C;
  long bm;
  int Kfull, Khalf;
  if (yb < 32) {
    bm = (long)yb * 128;
    A = Hs;
    Bt = swo_t;
    Kfull = FDIM;
    Khalf = FDIM / 2;
    C = racc + (long)blockIdx.z * T_TOK * DIM;
  } else {
    const int ty = yb - 32;
    if (ty >= *n_tiles) return;
    const int2 td = tdesc[ty];
    bm = td.y;
    A = Hr;
    Bt = ewo_t + (long)td.x * DIM * MDIM;
    Kfull = MDIM;
    Khalf = MDIM / 2;
    C = Hout + (long)blockIdx.z * HROWS * DIM;
  }
  __shared__ __align__(16) u16 As[2][128 * 32];  // 16 KB
  __shared__ __align__(16) u16 Bs[2][256 * 32];  // 32 KB
  const int tid = threadIdx.x;
  const int lane = tid & 63;
  const int wave = tid >> 6;
  const int wm = (wave >> 2) * 64;
  const int wn = (wave & 3) * 64;
  const long bn = (long)blockIdx.x * 256;
  const int kbase = blockIdx.z * Khalf;

  f32x4 acc[4][4] = {};
  const int r0 = tid >> 2;
  const int cs = ((tid & 3) ^ ((r0 >> 1) & 3)) * 8;
  const u16* Asrc = A + (bm + r0) * (long)Kfull + kbase + cs;
  const u16* Ba = Bt + (bn + r0) * (long)Kfull + kbase + cs;
  const u16* Bb = Bt + (bn + r0 + 128) * (long)Kfull + kbase + cs;
  const int fr = lane & 15;
  const int fq = lane >> 4;
  const int qs = (fq ^ ((fr >> 1) & 3)) * 8;

#define STAGE_OUT(buf, kt)                                \
  {                                                       \
    const int k0_ = (kt) * 32;                            \
    async_copy16(Asrc + k0_, &As[buf][tid * 8]);          \
    async_copy16(Ba + k0_, &Bs[buf][tid * 8]);            \
    async_copy16(Bb + k0_, &Bs[buf][(tid + 512) * 8]);    \
  }

  const int NT = Khalf / 32;  // 32 (shared) or 16 (routed)
  STAGE_OUT(0, 0);
  STAGE_OUT(1, 1);
  int cur = 0;
  for (int t = 0; t < NT; ++t) {
    if (t + 2 < NT) {
      asm volatile("s_waitcnt vmcnt(3)" ::: "memory");
    } else {
      asm volatile("s_waitcnt vmcnt(0)" ::: "memory");
    }
    __builtin_amdgcn_s_barrier();
    f16x8 af[4], bf[4];
    {
      const u16* Ap = &As[cur][0];
      const u16* Bp = &Bs[cur][0];
#pragma unroll
      for (int i = 0; i < 4; i++) {
        af[i] = ds_read128(Ap + (wm + i * 16 + fr) * 32 + qs);
        bf[i] = ds_read128(Bp + (wn + i * 16 + fr) * 32 + qs);
      }
    }
    asm volatile("s_waitcnt lgkmcnt(0)" ::: "memory");
    __builtin_amdgcn_sched_barrier(0);
    __builtin_amdgcn_s_barrier();
    if (t + 2 < NT) STAGE_OUT(cur, t + 2);
    __builtin_amdgcn_s_setprio(1);
#pragma unroll
    for (int mi = 0; mi < 4; mi++)
#pragma unroll
      for (int ni = 0; ni < 4; ni++)
        acc[mi][ni] = __builtin_amdgcn_mfma_f32_16x16x32_f16(af[mi], bf[ni], acc[mi][ni], 0, 0, 0);
    __builtin_amdgcn_s_setprio(0);
    cur ^= 1;
  }
#undef STAGE_OUT

  const int er = (lane >> 4) * 4;
  const int ec = lane & 15;
#pragma unroll
  for (int mi = 0; mi < 4; mi++)
#pragma unroll
    for (int r = 0; r < 4; r++) {
      const long row = bm + wm + mi * 16 + er + r;
#pragma unroll
      for (int ni = 0; ni < 4; ni++)
        C[row * DIM + bn + wn + ni * 16 + ec] = acc[mi][ni][r];
    }
}

// ---------------------------------------------------------------------------
// Transpose f32 [R,C] -> f16 [C,R]; dual-source variant batches over z.
// ---------------------------------------------------------------------------
__global__ __launch_bounds__(256) void transpose_cvt2(
    const float* __restrict__ s0, const float* __restrict__ s1,
    u16* __restrict__ dst, int R, int C, int zsplit) {
  __shared__ float tile[32][33];
  const int z = blockIdx.z;
  const float* src = (z < zsplit) ? s0 + (long)z * R * C
                                  : s1 + (long)(z - zsplit) * R * C;
  u16* d = dst + (long)z * R * C;
  const int c0 = blockIdx.x * 32, r0 = blockIdx.y * 32;
  const int tx = threadIdx.x & 31, ty = threadIdx.x >> 5;
#pragma unroll
  for (int i = 0; i < 32; i += 8) tile[ty + i][tx] = src[(long)(r0 + ty + i) * C + c0 + tx];
  __syncthreads();
#pragma unroll
  for (int i = 0; i < 32; i += 8) d[(long)(c0 + ty + i) * R + r0 + tx] = f2h(tile[tx][ty + i]);
}

// ---------------------------------------------------------------------------
// Router (+ folded x_sh f16 conversion): routed_in = rms_norm(orig,ln2s) f16;
// softmax/top2; eidx/ewt/probs. One block per token. No atomics.
// ---------------------------------------------------------------------------
__global__ __launch_bounds__(256) void router_kernel(
    const float* __restrict__ orig, const float* __restrict__ inputs,
    const float* __restrict__ pfs, const float* __restrict__ ln2s,
    const float* __restrict__ rw, u16* __restrict__ routed_in,
    u16* __restrict__ x_sh, int* __restrict__ eidx, float* __restrict__ ewt,
    float* __restrict__ probs_out) {
  const int t = blockIdx.x;
  const int tid = threadIdx.x;
  const int d = tid * 4;
  // folded cvt: inputs row -> f16
  {
    const float4 xi = *(const float4*)(inputs + (long)t * DIM + d);
    u16x4 xo = {f2h(xi.x), f2h(xi.y), f2h(xi.z), f2h(xi.w)};
    *(u16x4*)(x_sh + (long)t * DIM + d) = xo;
  }
  const float4 v = *(const float4*)(orig + (long)t * DIM + d);
  float ss = v.x * v.x + v.y * v.y + v.z * v.z + v.w * v.w;
#pragma unroll
  for (int off = 32; off > 0; off >>= 1) ss += __shfl_down(ss, off);
  __shared__ float red[4];
  __shared__ float lred[4][8];
  if ((tid & 63) == 0) red[tid >> 6] = ss;
  __syncthreads();
  const float rs = rsqrtf((red[0] + red[1] + red[2] + red[3]) * (1.0f / DIM) + 1e-6f);

  const float4 l2 = *(const float4*)(ln2s + d);
  u16x4 ro = {f2h(v.x * rs * l2.x), f2h(v.y * rs * l2.y), f2h(v.z * rs * l2.z),
              f2h(v.w * rs * l2.w)};
  *(u16x4*)(routed_in + (long)t * DIM + d) = ro;

  const float4 pf = *(const float4*)(pfs + d);
  const float c = rs * 0.03125f;  // D^-0.5
  const float g0 = v.x * c * pf.x, g1 = v.y * c * pf.y;
  const float g2 = v.z * c * pf.z, g3 = v.w * c * pf.w;
  float lg[8];
#pragma unroll
  for (int e = 0; e < 8; e++)
    lg[e] = g0 * rw[(d + 0) * 8 + e] + g1 * rw[(d + 1) * 8 + e] +
            g2 * rw[(d + 2) * 8 + e] + g3 * rw[(d + 3) * 8 + e];
#pragma unroll
  for (int e = 0; e < 8; e++)
#pragma unroll
    for (int off = 32; off > 0; off >>= 1) lg[e] += __shfl_down(lg[e], off);
  if ((tid & 63) == 0)
#pragma unroll
    for (int e = 0; e < 8; e++) lred[tid >> 6][e] = lg[e];
  __syncthreads();
  if (tid == 0) {
    float lz[8], p[8];
    float mx = -1e30f;
#pragma unroll
    for (int e = 0; e < 8; e++) {
      lz[e] = lred[0][e] + lred[1][e] + lred[2][e] + lred[3][e];
      mx = fmaxf(mx, lz[e]);
    }
    float s = 0.0f;
#pragma unroll
    for (int e = 0; e < 8; e++) {
      p[e] = expf(lz[e] - mx);
      s += p[e];
    }
    const float invs = 1.0f / s;
#pragma unroll
    for (int e = 0; e < 8; e++) p[e] *= invs;
    int i1 = 0;
    for (int e = 1; e < 8; e++)
      if (p[e] > p[i1]) i1 = e;  // strict > keeps lowest index (lax.top_k)
    int i2 = (i1 == 0) ? 1 : 0;
    for (int e = 0; e < 8; e++)
      if (e != i1 && p[e] > p[i2]) i2 = e;
    const float wsum = p[i1] + p[i2];
    eidx[2 * t] = i1;
    eidx[2 * t + 1] = i2;
    ewt[2 * t] = p[i1] / wsum;
    ewt[2 * t + 1] = p[i2] / wsum;
    float* prow = probs_out + (long)t * 8;
    for (int e = 0; e < 8; e++) prow[e] = p[e];
  }
}

// counts[e] += #assignments; LDS hist, 8 global atomics/block
__global__ __launch_bounds__(256) void bucket_count(const int* __restrict__ eidx,
                                                    int* __restrict__ counts) {
  __shared__ int lcnt[8];
  const int tid = threadIdx.x;
  if (tid < 8) lcnt[tid] = 0;
  __syncthreads();
  const int t = blockIdx.x * 256 + tid;
  atomicAdd(&lcnt[eidx[2 * t]], 1);
  atomicAdd(&lcnt[eidx[2 * t + 1]], 1);
  __syncthreads();
  if (tid < 8) atomicAdd(&counts[tid], lcnt[tid]);
}

__global__ void setup_tiles(const int* __restrict__ counts, int* __restrict__ poffset,
                            int2* __restrict__ tdesc, int* __restrict__ n_tiles) {
  if (threadIdx.x == 0 && blockIdx.x == 0) {
    int cur = 0, nt = 0;
    for (int e = 0; e < NEXP; e++) {
      poffset[e] = cur;
      const int ntile = (counts[e] + 127) >> 7;
      for (int i = 0; i < ntile; i++) {
        int2 d;
        d.x = e;
        d.y = cur + i * 128;
        tdesc[nt++] = d;
      }
      cur += ntile * 128;
    }
    n_tiles[0] = nt;
  }
}

__global__ __launch_bounds__(256) void bucket_scatter(
    const int* __restrict__ eidx, const int* __restrict__ poffset,
    int* __restrict__ cursors, int* __restrict__ ridx, int* __restrict__ pos) {
  __shared__ int lcnt[8], base[8];
  const int tid = threadIdx.x;
  if (tid < 8) lcnt[tid] = 0;
  __syncthreads();
  const int t = blockIdx.x * 256 + tid;
  const int e0 = eidx[2 * t], e1 = eidx[2 * t + 1];
  const int r0 = atomicAdd(&lcnt[e0], 1);
  const int r1 = atomicAdd(&lcnt[e1], 1);
  __syncthreads();
  if (tid < 8) base[tid] = atomicAdd(&cursors[tid], lcnt[tid]);
  __syncthreads();
  const int p0 = poffset[e0] + base[e0] + r0;
  const int p1 = poffset[e1] + base[e1] + r1;
  ridx[p0] = t;
  ridx[p1] = t;
  pos[2 * t] = p0;
  pos[2 * t + 1] = p1;
}

__global__ __launch_bounds__(256) void lb_reduce(const float* __restrict__ probs,
                                                 const int* __restrict__ counts,
                                                 float* __restrict__ out) {
  const int tid = threadIdx.x;
  float psum[8] = {};
  for (int tt = 0; tt < 16; tt++) {
    const long t = (long)tid * 16 + tt;
    const float4* pp = (const float4*)(probs + t * 8);
    const float4 p0 = pp[0], p1 = pp[1];
    psum[0] += p0.x; psum[1] += p0.y; psum[2] += p0.z; psum[3] += p0.w;
    psum[4] += p1.x; psum[5] += p1.y; psum[6] += p1.z; psum[7] += p1.w;
  }
#pragma unroll
  for (int e = 0; e < 8; e++)
#pragma unroll
    for (int off = 32; off > 0; off >>= 1) psum[e] += __shfl_down(psum[e], off);
  __shared__ float sp[4][8];
  if ((tid & 63) == 0)
#pragma unroll
    for (int e = 0; e < 8; e++) sp[tid >> 6][e] = psum[e];
  __syncthreads();
  if (tid == 0) {
    float loss = 0.0f;
#pragma unroll
    for (int e = 0; e < 8; e++) {
      const float fp = (sp[0][e] + sp[1][e] + sp[2][e] + sp[3][e]) / 4096.0f;
      const float ft = (float)counts[e] / (4096.0f * 2.0f);
      loss += ft * fp;
    }
    out[0] = 8.0f * loss;
  }
}

// ---------------------------------------------------------------------------
// Final epilogue: out = rms(shared_partials, post1) + rms(combined, post2).
// Single d_out write; sums split-K partials for both paths.
// ---------------------------------------------------------------------------
__global__ __launch_bounds__(256) void final_norm(
    const float* __restrict__ racc, const float* __restrict__ Hout,
    const int* __restrict__ pos, const float* __restrict__ ewt,
    const float* __restrict__ post1, const float* __restrict__ post2,
    float* __restrict__ out) {
  const int t = blockIdx.x;
  const int tid = threadIdx.x;
  const int d = tid * 4;
  const long base = (long)t * DIM + d;
  // shared path
  const float4 a = *(const float4*)(racc + base);
  const float4 b = *(const float4*)(racc + base + (long)T_TOK * DIM);
  float4 vs;
  vs.x = a.x + b.x; vs.y = a.y + b.y; vs.z = a.z + b.z; vs.w = a.w + b.w;
  // routed path
  const float w0 = ewt[2 * t], w1 = ewt[2 * t + 1];
  const long p0 = pos[2 * t], p1 = pos[2 * t + 1];
  const long SK = (long)HROWS * DIM;
  const float4 a0 = *(const float4*)(Hout + p0 * DIM + d);
  const float4 a1 = *(const float4*)(Hout + SK + p0 * DIM + d);
  const float4 b0 = *(const float4*)(Hout + p1 * DIM + d);
  const float4 b1 = *(const float4*)(Hout + SK + p1 * DIM + d);
  float4 vr;
  vr.x = w0 * (a0.x + a1.x) + w1 * (b0.x + b1.x);
  vr.y = w0 * (a0.y + a1.y) + w1 * (b0.y + b1.y);
  vr.z = w0 * (a0.z + a1.z) + w1 * (b0.z + b1.z);
  vr.w = w0 * (a0.w + a1.w) + w1 * (b0.w + b1.w);
  float ss = vs.x * vs.x + vs.y * vs.y + vs.z * vs.z + vs.w * vs.w;
  float sr = vr.x * vr.x + vr.y * vr.y + vr.z * vr.z + vr.w * vr.w;
#pragma unroll
  for (int off = 32; off > 0; off >>= 1) {
    ss += __shfl_down(ss, off);
    sr += __shfl_down(sr, off);
  }
  __shared__ float reds[4], redr[4];
  if ((tid & 63) == 0) {
    reds[tid >> 6] = ss;
    redr[tid >> 6] = sr;
  }
  __syncthreads();
  const float rss = rsqrtf((reds[0] + reds[1] + reds[2] + reds[3]) * (1.0f / DIM) + 1e-6f);
  const float rsr = rsqrtf((redr[0] + redr[1] + redr[2] + redr[3]) * (1.0f / DIM) + 1e-6f);
  const float4 s1 = *(const float4*)(post1 + d);
  const float4 s2 = *(const float4*)(post2 + d);
  float4 o;
  o.x = vs.x * rss * s1.x + vr.x * rsr * s2.x;
  o.y = vs.y * rss * s1.y + vr.y * rsr * s2.y;
  o.z = vs.z * rss * s1.z + vr.z * rsr * s2.z;
  o.w = vs.w * rss * s1.w + vr.w * rsr * s2.w;
  *(float4*)(out + base) = o;
}

// ---------------------------------------------------------------------------
extern "C" void kernel_launch(void* const* d_in, const int* in_sizes, int n_in,
                              void* d_out, int out_size, void* d_ws, size_t ws_size,
                              hipStream_t stream) {
  (void)in_sizes; (void)n_in; (void)out_size; (void)ws_size;
  const float* inputs   = (const float*)d_in[0];
  const float* orig     = (const float*)d_in[1];
  const float* pfs      = (const float*)d_in[2];
  const float* ln2s     = (const float*)d_in[3];
  const float* post1    = (const float*)d_in[4];
  const float* post2    = (const float*)d_in[5];
  const float* router_w = (const float*)d_in[6];
  const float* e_wi0    = (const float*)d_in[7];
  const float* e_wi1    = (const float*)d_in[8];
  const float* e_wo     = (const float*)d_in[9];
  const float* s_wi0    = (const float*)d_in[10];
  const float* s_wi1    = (const float*)d_in[11];
  const float* s_wo     = (const float*)d_in[12];

  char* ws = (char*)d_ws;
  size_t o = 0;
  auto alloc = [&](size_t bytes) -> void* {
    void* p = ws + o;
    o += (bytes + 255) & ~(size_t)255;
    return p;
  };
  u16* s_wi_t  = (u16*)alloc((size_t)2 * FDIM * DIM * 2);        // [2][F,D]
  u16* s_wo_t  = (u16*)alloc((size_t)DIM * FDIM * 2);            // [D,F]
  u16* e_wi_t  = (u16*)alloc((size_t)2 * NEXP * MDIM * DIM * 2); // [2][E,M,D]
  u16* e_wo_t  = (u16*)alloc((size_t)NEXP * DIM * MDIM * 2);     // [E,D,M]
  u16* x_sh    = (u16*)alloc((size_t)T_TOK * DIM * 2);
  u16* routed  = (u16*)alloc((size_t)T_TOK * DIM * 2);
  float* probs = (float*)alloc((size_t)T_TOK * 8 * 4);
  int* eidx    = (int*)alloc((size_t)T_TOK * 2 * 4);
  float* ewt   = (float*)alloc((size_t)T_TOK * 2 * 4);
  int* pos     = (int*)alloc((size_t)T_TOK * 2 * 4);
  int* imeta   = (int*)alloc(256);           // [0..7] counts, [8..15] cursors
  int* poffset = (int*)alloc(64);
  int* n_tiles = (int*)alloc(64);
  int2* tdesc  = (int2*)alloc(MAXTILES * 8);
  int* ridx    = (int*)alloc((size_t)HROWS * 4);
  float* racc  = (float*)alloc((size_t)2 * T_TOK * DIM * 4);     // split-K partials
  u16* Hs      = (u16*)alloc((size_t)T_TOK * FDIM * 2);          // gated h (shared)
  u16* H       = (u16*)alloc((size_t)HROWS * MDIM * 2);          // gated h (routed)
  float* Hout  = (float*)alloc((size_t)2 * HROWS * DIM * 4);     // split-K partials

  int* counts = imeta;
  int* cursors = imeta + 8;

  hipMemsetAsync(imeta, 0, 64, stream);
  hipMemsetAsync(ridx, 0, (size_t)HROWS * 4, stream);

  // ---- weight transposes (f32 -> f16 B^T layouts), 4 launches ----
  transpose_cvt2<<<dim3(FDIM / 32, DIM / 32, 2), 256, 0, stream>>>(
      s_wi0, s_wi1, s_wi_t, DIM, FDIM, 1);
  transpose_cvt2<<<dim3(DIM / 32, FDIM / 32, 1), 256, 0, stream>>>(
      s_wo, s_wo, s_wo_t, FDIM, DIM, 1);
  transpose_cvt2<<<dim3(MDIM / 32, DIM / 32, 16), 256, 0, stream>>>(
      e_wi0, e_wi1, e_wi_t, DIM, MDIM, 8);
  transpose_cvt2<<<dim3(DIM / 32, MDIM / 32, 8), 256, 0, stream>>>(
      e_wo, e_wo, e_wo_t, MDIM, DIM, 8);

  router_kernel<<<T_TOK, 256, 0, stream>>>(orig, inputs, pfs, ln2s, router_w,
                                           routed, x_sh, eidx, ewt, probs);

  // ---- bucketing ----
  bucket_count<<<16, 256, 0, stream>>>(eidx, counts);
  setup_tiles<<<1, 64, 0, stream>>>(counts, poffset, tdesc, n_tiles);
  bucket_scatter<<<16, 256, 0, stream>>>(eidx, poffset, cursors, ridx, pos);

  // ---- merged in-GEMM (shared + routed gated), pipelined ----
  gemm_in<<<dim3(FDIM / 256, 32 + MAXTILES, 1), 512, 0, stream>>>(
      x_sh, s_wi_t, routed, e_wi_t, Hs, H, ridx, tdesc, n_tiles);

  // ---- merged out-GEMM (shared + routed, split-K=2), pipelined ----
  gemm_out2<<<dim3(DIM / 256, 32 + MAXTILES, 2), 512, 0, stream>>>(
      Hs, s_wo_t, racc, H, e_wo_t, Hout, tdesc, n_tiles);

  // ---- fused final norm + combine ----
  final_norm<<<T_TOK, 256, 0, stream>>>(racc, Hout, pos, ewt, post1, post2,
                                        (float*)d_out);

  lb_reduce<<<1, 256, 0, stream>>>(probs, counts, (float*)d_out + (size_t)T_TOK * DIM);
}

// Round 3
// 431.856 us; speedup vs baseline: 1.0906x; 1.0906x over previous
//
#include <hip/hip_runtime.h>
#include <stdint.h>

// ---------------------------------------------------------------------------
// Gemma4 MoE block on gfx950. FP16 MFMA (16x16x32) GEMMs, f32 accumulation.
// R2: sparse top-2 routed experts (tile-padded bucketing + grouped GEMMs).
// R4: gated dual-GEMM, 256 thr, dual acc, BK=64, XOR source swizzle (0 bank
//     conflicts). R6: dispatch merging (one in-GEMM, one out-GEMM launch).
// R7/R8: counted-vmcnt pipeline attempts REGRESSED (m232 failure mode: a
//     hand counted-vmcnt loop without the full derived-waits 8-phase
//     schedule lands below the 2-phase ceiling). Reverted to R6 GEMM cores.
// R9: gemm_out2 split-K removed (z=1, full-K per block): halves f32 partial
//     writes (~52 MB), halves block count, doubles per-block K amortization;
//     final_norm reads single partials.
// ---------------------------------------------------------------------------

typedef unsigned short u16;
typedef u16 u16x4 __attribute__((ext_vector_type(4)));
typedef u16 u16x8 __attribute__((ext_vector_type(8)));
typedef _Float16 f16x8 __attribute__((ext_vector_type(8)));
typedef float f32x4 __attribute__((ext_vector_type(4)));
typedef __attribute__((address_space(1))) void* as1_vp;
typedef __attribute__((address_space(3))) void* as3_vp;

#define T_TOK 4096
#define DIM   1024
#define FDIM  2048
#define MDIM  1024
#define NEXP  8
#define MAXTILES 72            // sum ceil(cnt_e/128) <= 64 + 7, padded
#define HROWS (MAXTILES * 128) // 9216 padded assignment rows

__device__ __forceinline__ u16 f2h(float f) {
  _Float16 h = (_Float16)f;
  return __builtin_bit_cast(u16, h);
}
__device__ __forceinline__ float h2f(u16 u) {
  return (float)__builtin_bit_cast(_Float16, u);
}
// tanh-approx gelu rewritten exactly as x*sigmoid(2y): cheap __expf + div
__device__ __forceinline__ float gelu_f(float x) {
  const float y2 = x * (1.5957691216f + 0.0713548163f * x * x);
  return x / (1.0f + __expf(-y2));
}
__device__ __forceinline__ void async_copy16(const void* g, void* l) {
  __builtin_amdgcn_global_load_lds((as1_vp)(uintptr_t)g,
                                   (as3_vp)(uint32_t)(uintptr_t)l, 16, 0, 0);
}
__device__ __forceinline__ f16x8 lds_frag(const u16* p) {
  return __builtin_bit_cast(f16x8, *(const u16x8*)p);
}

// ---------------------------------------------------------------------------
// Merged gated dual-GEMM (shared + routed in ONE dispatch).
// H = gelu(A@B0) * (A@B1), f16. 256 thr / 4 waves (2x2 of 64x64), dual acc
// per wave (in-register gelu*mul). BK=64, 48 KB LDS, XOR source swizzle.
// blockIdx.y < 32: shared (A=x_sh, N=FDIM, all 16 x-blocks).
// blockIdx.y >= 32: routed tile (gather rows via ridx, N=MDIM, x < 8).
// K = DIM = 1024 for both.
// ---------------------------------------------------------------------------
__global__ __launch_bounds__(256, 2) void gemm_in(
    const u16* __restrict__ xs, const u16* __restrict__ swi_t,
    const u16* __restrict__ routed, const u16* __restrict__ ewi_t,
    u16* __restrict__ Hs, u16* __restrict__ Hr,
    const int* __restrict__ ridx, const int2* __restrict__ tdesc,
    const int* __restrict__ n_tiles) {
  const int yb = (int)blockIdx.y;
  const u16 *A, *B0t, *B1t;
  u16* H;
  int N;
  long bm;
  bool gather;
  if (yb < 32) {
    bm = (long)yb * 128;
    A = xs;
    B0t = swi_t;
    B1t = swi_t + (size_t)FDIM * DIM;
    H = Hs;
    N = FDIM;
    gather = false;
  } else {
    const int ty = yb - 32;
    if (ty >= *n_tiles) return;
    if ((int)blockIdx.x >= MDIM / 128) return;
    const int2 td = tdesc[ty];
    bm = td.y;
    A = routed;
    B0t = ewi_t + (long)td.x * MDIM * DIM;
    B1t = ewi_t + (size_t)NEXP * MDIM * DIM + (long)td.x * MDIM * DIM;
    H = Hr;
    N = MDIM;
    gather = true;
  }
  __shared__ __align__(16) u16 As[128 * 64];   // 16 KB
  __shared__ __align__(16) u16 Bs0[128 * 64];  // 16 KB
  __shared__ __align__(16) u16 Bs1[128 * 64];  // 16 KB
  const int tid = threadIdx.x;
  const int lane = tid & 63;
  const int wave = tid >> 6;
  const int wm = (wave >> 1) * 64;
  const int wn = (wave & 1) * 64;
  const long bn = (long)blockIdx.x * 128;

  f32x4 acc0[4][4] = {}, acc1[4][4] = {};

  // Staging: slot s = (row, swizzled chunk); lane-linear LDS dest, swizzle on
  // global source index (validated R5: SQ_LDS_BANK_CONFLICT = 0).
  const int r0 = tid >> 3;
  const int cc = ((tid & 7) ^ (r0 & 7)) * 8;
  const long rowstride = 32 * (long)DIM;
  const u16* Ag[4];
  if (gather) {
#pragma unroll
    for (int i = 0; i < 4; i++) Ag[i] = A + (long)ridx[bm + r0 + i * 32] * DIM + cc;
  } else {
#pragma unroll
    for (int i = 0; i < 4; i++) Ag[i] = A + (bm + r0 + i * 32) * (long)DIM + cc;
  }
  const u16* B0g = B0t + (bn + r0) * (long)DIM + cc;
  const u16* B1g = B1t + (bn + r0) * (long)DIM + cc;
  const int fr = lane & 15;
  const int fq = lane >> 4;

  for (int k0 = 0; k0 < DIM; k0 += 64) {
#pragma unroll
    for (int i = 0; i < 4; i++) {
      async_copy16(Ag[i] + k0, &As[tid * 8 + i * 2048]);
      async_copy16(B0g + i * rowstride + k0, &Bs0[tid * 8 + i * 2048]);
      async_copy16(B1g + i * rowstride + k0, &Bs1[tid * 8 + i * 2048]);
    }
    __syncthreads();
#pragma unroll
    for (int kc = 0; kc < 8; kc += 4) {
      f16x8 af[4], b0[4], b1[4];
      const int q = (fq + kc) ^ (fr & 7);
#pragma unroll
      for (int i = 0; i < 4; i++) {
        af[i] = lds_frag(&As[(wm + i * 16 + fr) * 64 + q * 8]);
        b0[i] = lds_frag(&Bs0[(wn + i * 16 + fr) * 64 + q * 8]);
        b1[i] = lds_frag(&Bs1[(wn + i * 16 + fr) * 64 + q * 8]);
      }
#pragma unroll
      for (int mi = 0; mi < 4; mi++)
#pragma unroll
        for (int ni = 0; ni < 4; ni++) {
          acc0[mi][ni] = __builtin_amdgcn_mfma_f32_16x16x32_f16(af[mi], b0[ni], acc0[mi][ni], 0, 0, 0);
          acc1[mi][ni] = __builtin_amdgcn_mfma_f32_16x16x32_f16(af[mi], b1[ni], acc1[mi][ni], 0, 0, 0);
        }
    }
    __syncthreads();
  }

  const int er = (lane >> 4) * 4;  // C/D: col=lane&15, row=(lane>>4)*4+reg
  const int ec = lane & 15;
#pragma unroll
  for (int mi = 0; mi < 4; mi++)
#pragma unroll
    for (int r = 0; r < 4; r++) {
      const long row = bm + wm + mi * 16 + er + r;
#pragma unroll
      for (int ni = 0; ni < 4; ni++)
        H[row * N + bn + wn + ni * 16 + ec] =
            f2h(gelu_f(acc0[mi][ni][r]) * acc1[mi][ni][r]);
    }
}

// ---------------------------------------------------------------------------
// Merged out-GEMM (shared + routed), BK=64 + swizzle, full-K (no split-K).
// y<32: shared A=Hs (K=FDIM), C=racc. y>=32: routed tile (padded positions,
// K=MDIM), C=Hout. N = DIM for both.
// ---------------------------------------------------------------------------
__global__ __launch_bounds__(256) void gemm_out2(
    const u16* __restrict__ Hs, const u16* __restrict__ swo_t,
    float* __restrict__ racc, const u16* __restrict__ Hr,
    const u16* __restrict__ ewo_t, float* __restrict__ Hout,
    const int2* __restrict__ tdesc, const int* __restrict__ n_tiles) {
  const int yb = (int)blockIdx.y;
  const u16 *A, *Bt;
  float* C;
  long bm;
  int K;
  if (yb < 32) {
    bm = (long)yb * 128;
    A = Hs;
    Bt = swo_t;
    K = FDIM;
    C = racc;
  } else {
    const int ty = yb - 32;
    if (ty >= *n_tiles) return;
    const int2 td = tdesc[ty];
    bm = td.y;
    A = Hr;
    Bt = ewo_t + (long)td.x * DIM * MDIM;
    K = MDIM;
    C = Hout;
  }
  __shared__ __align__(16) u16 As[128 * 64];  // 16 KB
  __shared__ __align__(16) u16 Bs[128 * 64];  // 16 KB
  const int tid = threadIdx.x;
  const int lane = tid & 63;
  const int wave = tid >> 6;
  const int wm = (wave >> 1) * 64;
  const int wn = (wave & 1) * 64;
  const long bn = (long)blockIdx.x * 128;

  f32x4 acc[4][4] = {};
  const int r0 = tid >> 3;
  const int cc = ((tid & 7) ^ (r0 & 7)) * 8;
  const long rowstride = 32 * (long)K;
  const u16* Ag[4];
#pragma unroll
  for (int i = 0; i < 4; i++) Ag[i] = A + (bm + r0 + i * 32) * (long)K + cc;
  const u16* Bg = Bt + (bn + r0) * (long)K + cc;
  const int fr = lane & 15;
  const int fq = lane >> 4;

  for (int k0 = 0; k0 < K; k0 += 64) {
#pragma unroll
    for (int i = 0; i < 4; i++) {
      async_copy16(Ag[i] + k0, &As[tid * 8 + i * 2048]);
      async_copy16(Bg + i * rowstride + k0, &Bs[tid * 8 + i * 2048]);
    }
    __syncthreads();
#pragma unroll
    for (int kc = 0; kc < 8; kc += 4) {
      f16x8 af[4], bq[4];
      const int q = (fq + kc) ^ (fr & 7);
#pragma unroll
      for (int i = 0; i < 4; i++) {
        af[i] = lds_frag(&As[(wm + i * 16 + fr) * 64 + q * 8]);
        bq[i] = lds_frag(&Bs[(wn + i * 16 + fr) * 64 + q * 8]);
      }
#pragma unroll
      for (int mi = 0; mi < 4; mi++)
#pragma unroll
        for (int ni = 0; ni < 4; ni++)
          acc[mi][ni] = __builtin_amdgcn_mfma_f32_16x16x32_f16(af[mi], bq[ni], acc[mi][ni], 0, 0, 0);
    }
    __syncthreads();
  }

  const int er = (lane >> 4) * 4;
  const int ec = lane & 15;
#pragma unroll
  for (int mi = 0; mi < 4; mi++)
#pragma unroll
    for (int r = 0; r < 4; r++) {
      const long row = bm + wm + mi * 16 + er + r;
#pragma unroll
      for (int ni = 0; ni < 4; ni++)
        C[row * DIM + bn + wn + ni * 16 + ec] = acc[mi][ni][r];
    }
}

// ---------------------------------------------------------------------------
// Transpose f32 [R,C] -> f16 [C,R]; dual-source variant batches over z.
// ---------------------------------------------------------------------------
__global__ __launch_bounds__(256) void transpose_cvt2(
    const float* __restrict__ s0, const float* __restrict__ s1,
    u16* __restrict__ dst, int R, int C, int zsplit) {
  __shared__ float tile[32][33];
  const int z = blockIdx.z;
  const float* src = (z < zsplit) ? s0 + (long)z * R * C
                                  : s1 + (long)(z - zsplit) * R * C;
  u16* d = dst + (long)z * R * C;
  const int c0 = blockIdx.x * 32, r0 = blockIdx.y * 32;
  const int tx = threadIdx.x & 31, ty = threadIdx.x >> 5;
#pragma unroll
  for (int i = 0; i < 32; i += 8) tile[ty + i][tx] = src[(long)(r0 + ty + i) * C + c0 + tx];
  __syncthreads();
#pragma unroll
  for (int i = 0; i < 32; i += 8) d[(long)(c0 + ty + i) * R + r0 + tx] = f2h(tile[tx][ty + i]);
}

// ---------------------------------------------------------------------------
// Router (+ folded x_sh f16 conversion): routed_in = rms_norm(orig,ln2s) f16;
// softmax/top2; eidx/ewt/probs. One block per token. No atomics.
// ---------------------------------------------------------------------------
__global__ __launch_bounds__(256) void router_kernel(
    const float* __restrict__ orig, const float* __restrict__ inputs,
    const float* __restrict__ pfs, const float* __restrict__ ln2s,
    const float* __restrict__ rw, u16* __restrict__ routed_in,
    u16* __restrict__ x_sh, int* __restrict__ eidx, float* __restrict__ ewt,
    float* __restrict__ probs_out) {
  const int t = blockIdx.x;
  const int tid = threadIdx.x;
  const int d = tid * 4;
  // folded cvt: inputs row -> f16
  {
    const float4 xi = *(const float4*)(inputs + (long)t * DIM + d);
    u16x4 xo = {f2h(xi.x), f2h(xi.y), f2h(xi.z), f2h(xi.w)};
    *(u16x4*)(x_sh + (long)t * DIM + d) = xo;
  }
  const float4 v = *(const float4*)(orig + (long)t * DIM + d);
  float ss = v.x * v.x + v.y * v.y + v.z * v.z + v.w * v.w;
#pragma unroll
  for (int off = 32; off > 0; off >>= 1) ss += __shfl_down(ss, off);
  __shared__ float red[4];
  __shared__ float lred[4][8];
  if ((tid & 63) == 0) red[tid >> 6] = ss;
  __syncthreads();
  const float rs = rsqrtf((red[0] + red[1] + red[2] + red[3]) * (1.0f / DIM) + 1e-6f);

  const float4 l2 = *(const float4*)(ln2s + d);
  u16x4 ro = {f2h(v.x * rs * l2.x), f2h(v.y * rs * l2.y), f2h(v.z * rs * l2.z),
              f2h(v.w * rs * l2.w)};
  *(u16x4*)(routed_in + (long)t * DIM + d) = ro;

  const float4 pf = *(const float4*)(pfs + d);
  const float c = rs * 0.03125f;  // D^-0.5
  const float g0 = v.x * c * pf.x, g1 = v.y * c * pf.y;
  const float g2 = v.z * c * pf.z, g3 = v.w * c * pf.w;
  float lg[8];
#pragma unroll
  for (int e = 0; e < 8; e++)
    lg[e] = g0 * rw[(d + 0) * 8 + e] + g1 * rw[(d + 1) * 8 + e] +
            g2 * rw[(d + 2) * 8 + e] + g3 * rw[(d + 3) * 8 + e];
#pragma unroll
  for (int e = 0; e < 8; e++)
#pragma unroll
    for (int off = 32; off > 0; off >>= 1) lg[e] += __shfl_down(lg[e], off);
  if ((tid & 63) == 0)
#pragma unroll
    for (int e = 0; e < 8; e++) lred[tid >> 6][e] = lg[e];
  __syncthreads();
  if (tid == 0) {
    float lz[8], p[8];
    float mx = -1e30f;
#pragma unroll
    for (int e = 0; e < 8; e++) {
      lz[e] = lred[0][e] + lred[1][e] + lred[2][e] + lred[3][e];
      mx = fmaxf(mx, lz[e]);
    }
    float s = 0.0f;
#pragma unroll
    for (int e = 0; e < 8; e++) {
      p[e] = expf(lz[e] - mx);
      s += p[e];
    }
    const float invs = 1.0f / s;
#pragma unroll
    for (int e = 0; e < 8; e++) p[e] *= invs;
    int i1 = 0;
    for (int e = 1; e < 8; e++)
      if (p[e] > p[i1]) i1 = e;  // strict > keeps lowest index (lax.top_k)
    int i2 = (i1 == 0) ? 1 : 0;
    for (int e = 0; e < 8; e++)
      if (e != i1 && p[e] > p[i2]) i2 = e;
    const float wsum = p[i1] + p[i2];
    eidx[2 * t] = i1;
    eidx[2 * t + 1] = i2;
    ewt[2 * t] = p[i1] / wsum;
    ewt[2 * t + 1] = p[i2] / wsum;
    float* prow = probs_out + (long)t * 8;
    for (int e = 0; e < 8; e++) prow[e] = p[e];
  }
}

// counts[e] += #assignments; LDS hist, 8 global atomics/block
__global__ __launch_bounds__(256) void bucket_count(const int* __restrict__ eidx,
                                                    int* __restrict__ counts) {
  __shared__ int lcnt[8];
  const int tid = threadIdx.x;
  if (tid < 8) lcnt[tid] = 0;
  __syncthreads();
  const int t = blockIdx.x * 256 + tid;
  atomicAdd(&lcnt[eidx[2 * t]], 1);
  atomicAdd(&lcnt[eidx[2 * t + 1]], 1);
  __syncthreads();
  if (tid < 8) atomicAdd(&counts[tid], lcnt[tid]);
}

__global__ void setup_tiles(const int* __restrict__ counts, int* __restrict__ poffset,
                            int2* __restrict__ tdesc, int* __restrict__ n_tiles) {
  if (threadIdx.x == 0 && blockIdx.x == 0) {
    int cur = 0, nt = 0;
    for (int e = 0; e < NEXP; e++) {
      poffset[e] = cur;
      const int ntile = (counts[e] + 127) >> 7;
      for (int i = 0; i < ntile; i++) {
        int2 d;
        d.x = e;
        d.y = cur + i * 128;
        tdesc[nt++] = d;
      }
      cur += ntile * 128;
    }
    n_tiles[0] = nt;
  }
}

__global__ __launch_bounds__(256) void bucket_scatter(
    const int* __restrict__ eidx, const int* __restrict__ poffset,
    int* __restrict__ cursors, int* __restrict__ ridx, int* __restrict__ pos) {
  __shared__ int lcnt[8], base[8];
  const int tid = threadIdx.x;
  if (tid < 8) lcnt[tid] = 0;
  __syncthreads();
  const int t = blockIdx.x * 256 + tid;
  const int e0 = eidx[2 * t], e1 = eidx[2 * t + 1];
  const int r0 = atomicAdd(&lcnt[e0], 1);
  const int r1 = atomicAdd(&lcnt[e1], 1);
  __syncthreads();
  if (tid < 8) base[tid] = atomicAdd(&cursors[tid], lcnt[tid]);
  __syncthreads();
  const int p0 = poffset[e0] + base[e0] + r0;
  const int p1 = poffset[e1] + base[e1] + r1;
  ridx[p0] = t;
  ridx[p1] = t;
  pos[2 * t] = p0;
  pos[2 * t + 1] = p1;
}

__global__ __launch_bounds__(256) void lb_reduce(const float* __restrict__ probs,
                                                 const int* __restrict__ counts,
                                                 float* __restrict__ out) {
  const int tid = threadIdx.x;
  float psum[8] = {};
  for (int tt = 0; tt < 16; tt++) {
    const long t = (long)tid * 16 + tt;
    const float4* pp = (const float4*)(probs + t * 8);
    const float4 p0 = pp[0], p1 = pp[1];
    psum[0] += p0.x; psum[1] += p0.y; psum[2] += p0.z; psum[3] += p0.w;
    psum[4] += p1.x; psum[5] += p1.y; psum[6] += p1.z; psum[7] += p1.w;
  }
#pragma unroll
  for (int e = 0; e < 8; e++)
#pragma unroll
    for (int off = 32; off > 0; off >>= 1) psum[e] += __shfl_down(psum[e], off);
  __shared__ float sp[4][8];
  if ((tid & 63) == 0)
#pragma unroll
    for (int e = 0; e < 8; e++) sp[tid >> 6][e] = psum[e];
  __syncthreads();
  if (tid == 0) {
    float loss = 0.0f;
#pragma unroll
    for (int e = 0; e < 8; e++) {
      const float fp = (sp[0][e] + sp[1][e] + sp[2][e] + sp[3][e]) / 4096.0f;
      const float ft = (float)counts[e] / (4096.0f * 2.0f);
      loss += ft * fp;
    }
    out[0] = 8.0f * loss;
  }
}

// ---------------------------------------------------------------------------
// Final epilogue: out = rms(shared, post1) + rms(combined routed, post2).
// Single d_out write; single (non-split) partials.
// ---------------------------------------------------------------------------
__global__ __launch_bounds__(256) void final_norm(
    const float* __restrict__ racc, const float* __restrict__ Hout,
    const int* __restrict__ pos, const float* __restrict__ ewt,
    const float* __restrict__ post1, const float* __restrict__ post2,
    float* __restrict__ out) {
  const int t = blockIdx.x;
  const int tid = threadIdx.x;
  const int d = tid * 4;
  const long base = (long)t * DIM + d;
  // shared path
  const float4 vs = *(const float4*)(racc + base);
  // routed path
  const float w0 = ewt[2 * t], w1 = ewt[2 * t + 1];
  const long p0 = pos[2 * t], p1 = pos[2 * t + 1];
  const float4 a0 = *(const float4*)(Hout + p0 * DIM + d);
  const float4 b0 = *(const float4*)(Hout + p1 * DIM + d);
  float4 vr;
  vr.x = w0 * a0.x + w1 * b0.x;
  vr.y = w0 * a0.y + w1 * b0.y;
  vr.z = w0 * a0.z + w1 * b0.z;
  vr.w = w0 * a0.w + w1 * b0.w;
  float ss = vs.x * vs.x + vs.y * vs.y + vs.z * vs.z + vs.w * vs.w;
  float sr = vr.x * vr.x + vr.y * vr.y + vr.z * vr.z + vr.w * vr.w;
#pragma unroll
  for (int off = 32; off > 0; off >>= 1) {
    ss += __shfl_down(ss, off);
    sr += __shfl_down(sr, off);
  }
  __shared__ float reds[4], redr[4];
  if ((tid & 63) == 0) {
    reds[tid >> 6] = ss;
    redr[tid >> 6] = sr;
  }
  __syncthreads();
  const float rss = rsqrtf((reds[0] + reds[1] + reds[2] + reds[3]) * (1.0f / DIM) + 1e-6f);
  const float rsr = rsqrtf((redr[0] + redr[1] + redr[2] + redr[3]) * (1.0f / DIM) + 1e-6f);
  const float4 s1 = *(const float4*)(post1 + d);
  const float4 s2 = *(const float4*)(post2 + d);
  float4 o;
  o.x = vs.x * rss * s1.x + vr.x * rsr * s2.x;
  o.y = vs.y * rss * s1.y + vr.y * rsr * s2.y;
  o.z = vs.z * rss * s1.z + vr.z * rsr * s2.z;
  o.w = vs.w * rss * s1.w + vr.w * rsr * s2.w;
  *(float4*)(out + base) = o;
}

// ---------------------------------------------------------------------------
extern "C" void kernel_launch(void* const* d_in, const int* in_sizes, int n_in,
                              void* d_out, int out_size, void* d_ws, size_t ws_size,
                              hipStream_t stream) {
  (void)in_sizes; (void)n_in; (void)out_size; (void)ws_size;
  const float* inputs   = (const float*)d_in[0];
  const float* orig     = (const float*)d_in[1];
  const float* pfs      = (const float*)d_in[2];
  const float* ln2s     = (const float*)d_in[3];
  const float* post1    = (const float*)d_in[4];
  const float* post2    = (const float*)d_in[5];
  const float* router_w = (const float*)d_in[6];
  const float* e_wi0    = (const float*)d_in[7];
  const float* e_wi1    = (const float*)d_in[8];
  const float* e_wo     = (const float*)d_in[9];
  const float* s_wi0    = (const float*)d_in[10];
  const float* s_wi1    = (const float*)d_in[11];
  const float* s_wo     = (const float*)d_in[12];

  char* ws = (char*)d_ws;
  size_t o = 0;
  auto alloc = [&](size_t bytes) -> void* {
    void* p = ws + o;
    o += (bytes + 255) & ~(size_t)255;
    return p;
  };
  u16* s_wi_t  = (u16*)alloc((size_t)2 * FDIM * DIM * 2);        // [2][F,D]
  u16* s_wo_t  = (u16*)alloc((size_t)DIM * FDIM * 2);            // [D,F]
  u16* e_wi_t  = (u16*)alloc((size_t)2 * NEXP * MDIM * DIM * 2); // [2][E,M,D]
  u16* e_wo_t  = (u16*)alloc((size_t)NEXP * DIM * MDIM * 2);     // [E,D,M]
  u16* x_sh    = (u16*)alloc((size_t)T_TOK * DIM * 2);
  u16* routed  = (u16*)alloc((size_t)T_TOK * DIM * 2);
  float* probs = (float*)alloc((size_t)T_TOK * 8 * 4);
  int* eidx    = (int*)alloc((size_t)T_TOK * 2 * 4);
  float* ewt   = (float*)alloc((size_t)T_TOK * 2 * 4);
  int* pos     = (int*)alloc((size_t)T_TOK * 2 * 4);
  int* imeta   = (int*)alloc(256);           // [0..7] counts, [8..15] cursors
  int* poffset = (int*)alloc(64);
  int* n_tiles = (int*)alloc(64);
  int2* tdesc  = (int2*)alloc(MAXTILES * 8);
  int* ridx    = (int*)alloc((size_t)HROWS * 4);
  float* racc  = (float*)alloc((size_t)T_TOK * DIM * 4);         // shared out (f32)
  u16* Hs      = (u16*)alloc((size_t)T_TOK * FDIM * 2);          // gated h (shared)
  u16* H       = (u16*)alloc((size_t)HROWS * MDIM * 2);          // gated h (routed)
  float* Hout  = (float*)alloc((size_t)HROWS * DIM * 4);         // routed out (f32)

  int* counts = imeta;
  int* cursors = imeta + 8;

  hipMemsetAsync(imeta, 0, 64, stream);
  hipMemsetAsync(ridx, 0, (size_t)HROWS * 4, stream);

  // ---- weight transposes (f32 -> f16 B^T layouts), 4 launches ----
  transpose_cvt2<<<dim3(FDIM / 32, DIM / 32, 2), 256, 0, stream>>>(
      s_wi0, s_wi1, s_wi_t, DIM, FDIM, 1);
  transpose_cvt2<<<dim3(DIM / 32, FDIM / 32, 1), 256, 0, stream>>>(
      s_wo, s_wo, s_wo_t, FDIM, DIM, 1);
  transpose_cvt2<<<dim3(MDIM / 32, DIM / 32, 16), 256, 0, stream>>>(
      e_wi0, e_wi1, e_wi_t, DIM, MDIM, 8);
  transpose_cvt2<<<dim3(DIM / 32, MDIM / 32, 8), 256, 0, stream>>>(
      e_wo, e_wo, e_wo_t, MDIM, DIM, 8);

  router_kernel<<<T_TOK, 256, 0, stream>>>(orig, inputs, pfs, ln2s, router_w,
                                           routed, x_sh, eidx, ewt, probs);

  // ---- bucketing ----
  bucket_count<<<16, 256, 0, stream>>>(eidx, counts);
  setup_tiles<<<1, 64, 0, stream>>>(counts, poffset, tdesc, n_tiles);
  bucket_scatter<<<16, 256, 0, stream>>>(eidx, poffset, cursors, ridx, pos);

  // ---- merged in-GEMM (shared + routed gated) ----
  gemm_in<<<dim3(FDIM / 128, 32 + MAXTILES, 1), 256, 0, stream>>>(
      x_sh, s_wi_t, routed, e_wi_t, Hs, H, ridx, tdesc, n_tiles);

  // ---- merged out-GEMM (shared + routed, full-K) ----
  gemm_out2<<<dim3(DIM / 128, 32 + MAXTILES, 1), 256, 0, stream>>>(
      Hs, s_wo_t, racc, H, e_wo_t, Hout, tdesc, n_tiles);

  // ---- fused final norm + combine ----
  final_norm<<<T_TOK, 256, 0, stream>>>(racc, Hout, pos, ewt, post1, post2,
                                        (float*)d_out);

  lb_reduce<<<1, 256, 0, stream>>>(probs, counts, (float*)d_out + (size_t)T_TOK * DIM);
}

// Round 4
// 423.537 us; speedup vs baseline: 1.1120x; 1.0196x over previous
//
#include <hip/hip_runtime.h>
#include <stdint.h>

// ---------------------------------------------------------------------------
// Gemma4 MoE block on gfx950. FP16 MFMA (16x16x32) GEMMs, f32 accumulation.
// R2: sparse top-2 routed experts (tile-padded bucketing + grouped GEMMs).
// R4: gated dual-GEMM, 256 thr, dual acc, BK=64, XOR source swizzle (0 bank
//     conflicts). R6: dispatch merging (one in-GEMM, one out-GEMM launch).
// R7/R8: counted-vmcnt pipeline attempts REGRESSED (m232 failure mode).
// R9: gemm_out2 split-K removed (full-K per block, single f32 C write).
// R10: transpose_cvt2 rewritten: 64x64 tiles, float4 loads, LDS [64][65]
//      (2-way bank aliasing = free), u16x8 16B stores. Old version used
//      scalar 2B f16 stores (G13 violation, ~2x slow on 60 MB of writes).
// ---------------------------------------------------------------------------

typedef unsigned short u16;
typedef u16 u16x4 __attribute__((ext_vector_type(4)));
typedef u16 u16x8 __attribute__((ext_vector_type(8)));
typedef _Float16 f16x8 __attribute__((ext_vector_type(8)));
typedef float f32x4 __attribute__((ext_vector_type(4)));
typedef __attribute__((address_space(1))) void* as1_vp;
typedef __attribute__((address_space(3))) void* as3_vp;

#define T_TOK 4096
#define DIM   1024
#define FDIM  2048
#define MDIM  1024
#define NEXP  8
#define MAXTILES 72            // sum ceil(cnt_e/128) <= 64 + 7, padded
#define HROWS (MAXTILES * 128) // 9216 padded assignment rows

__device__ __forceinline__ u16 f2h(float f) {
  _Float16 h = (_Float16)f;
  return __builtin_bit_cast(u16, h);
}
__device__ __forceinline__ float h2f(u16 u) {
  return (float)__builtin_bit_cast(_Float16, u);
}
// tanh-approx gelu rewritten exactly as x*sigmoid(2y): cheap __expf + div
__device__ __forceinline__ float gelu_f(float x) {
  const float y2 = x * (1.5957691216f + 0.0713548163f * x * x);
  return x / (1.0f + __expf(-y2));
}
__device__ __forceinline__ void async_copy16(const void* g, void* l) {
  __builtin_amdgcn_global_load_lds((as1_vp)(uintptr_t)g,
                                   (as3_vp)(uint32_t)(uintptr_t)l, 16, 0, 0);
}
__device__ __forceinline__ f16x8 lds_frag(const u16* p) {
  return __builtin_bit_cast(f16x8, *(const u16x8*)p);
}

// ---------------------------------------------------------------------------
// Merged gated dual-GEMM (shared + routed in ONE dispatch).
// H = gelu(A@B0) * (A@B1), f16. 256 thr / 4 waves (2x2 of 64x64), dual acc
// per wave (in-register gelu*mul). BK=64, 48 KB LDS, XOR source swizzle.
// blockIdx.y < 32: shared (A=x_sh, N=FDIM, all 16 x-blocks).
// blockIdx.y >= 32: routed tile (gather rows via ridx, N=MDIM, x < 8).
// K = DIM = 1024 for both.
// ---------------------------------------------------------------------------
__global__ __launch_bounds__(256, 2) void gemm_in(
    const u16* __restrict__ xs, const u16* __restrict__ swi_t,
    const u16* __restrict__ routed, const u16* __restrict__ ewi_t,
    u16* __restrict__ Hs, u16* __restrict__ Hr,
    const int* __restrict__ ridx, const int2* __restrict__ tdesc,
    const int* __restrict__ n_tiles) {
  const int yb = (int)blockIdx.y;
  const u16 *A, *B0t, *B1t;
  u16* H;
  int N;
  long bm;
  bool gather;
  if (yb < 32) {
    bm = (long)yb * 128;
    A = xs;
    B0t = swi_t;
    B1t = swi_t + (size_t)FDIM * DIM;
    H = Hs;
    N = FDIM;
    gather = false;
  } else {
    const int ty = yb - 32;
    if (ty >= *n_tiles) return;
    if ((int)blockIdx.x >= MDIM / 128) return;
    const int2 td = tdesc[ty];
    bm = td.y;
    A = routed;
    B0t = ewi_t + (long)td.x * MDIM * DIM;
    B1t = ewi_t + (size_t)NEXP * MDIM * DIM + (long)td.x * MDIM * DIM;
    H = Hr;
    N = MDIM;
    gather = true;
  }
  __shared__ __align__(16) u16 As[128 * 64];   // 16 KB
  __shared__ __align__(16) u16 Bs0[128 * 64];  // 16 KB
  __shared__ __align__(16) u16 Bs1[128 * 64];  // 16 KB
  const int tid = threadIdx.x;
  const int lane = tid & 63;
  const int wave = tid >> 6;
  const int wm = (wave >> 1) * 64;
  const int wn = (wave & 1) * 64;
  const long bn = (long)blockIdx.x * 128;

  f32x4 acc0[4][4] = {}, acc1[4][4] = {};

  // Staging: slot s = (row, swizzled chunk); lane-linear LDS dest, swizzle on
  // global source index (validated R5: SQ_LDS_BANK_CONFLICT = 0).
  const int r0 = tid >> 3;
  const int cc = ((tid & 7) ^ (r0 & 7)) * 8;
  const long rowstride = 32 * (long)DIM;
  const u16* Ag[4];
  if (gather) {
#pragma unroll
    for (int i = 0; i < 4; i++) Ag[i] = A + (long)ridx[bm + r0 + i * 32] * DIM + cc;
  } else {
#pragma unroll
    for (int i = 0; i < 4; i++) Ag[i] = A + (bm + r0 + i * 32) * (long)DIM + cc;
  }
  const u16* B0g = B0t + (bn + r0) * (long)DIM + cc;
  const u16* B1g = B1t + (bn + r0) * (long)DIM + cc;
  const int fr = lane & 15;
  const int fq = lane >> 4;

  for (int k0 = 0; k0 < DIM; k0 += 64) {
#pragma unroll
    for (int i = 0; i < 4; i++) {
      async_copy16(Ag[i] + k0, &As[tid * 8 + i * 2048]);
      async_copy16(B0g + i * rowstride + k0, &Bs0[tid * 8 + i * 2048]);
      async_copy16(B1g + i * rowstride + k0, &Bs1[tid * 8 + i * 2048]);
    }
    __syncthreads();
#pragma unroll
    for (int kc = 0; kc < 8; kc += 4) {
      f16x8 af[4], b0[4], b1[4];
      const int q = (fq + kc) ^ (fr & 7);
#pragma unroll
      for (int i = 0; i < 4; i++) {
        af[i] = lds_frag(&As[(wm + i * 16 + fr) * 64 + q * 8]);
        b0[i] = lds_frag(&Bs0[(wn + i * 16 + fr) * 64 + q * 8]);
        b1[i] = lds_frag(&Bs1[(wn + i * 16 + fr) * 64 + q * 8]);
      }
#pragma unroll
      for (int mi = 0; mi < 4; mi++)
#pragma unroll
        for (int ni = 0; ni < 4; ni++) {
          acc0[mi][ni] = __builtin_amdgcn_mfma_f32_16x16x32_f16(af[mi], b0[ni], acc0[mi][ni], 0, 0, 0);
          acc1[mi][ni] = __builtin_amdgcn_mfma_f32_16x16x32_f16(af[mi], b1[ni], acc1[mi][ni], 0, 0, 0);
        }
    }
    __syncthreads();
  }

  const int er = (lane >> 4) * 4;  // C/D: col=lane&15, row=(lane>>4)*4+reg
  const int ec = lane & 15;
#pragma unroll
  for (int mi = 0; mi < 4; mi++)
#pragma unroll
    for (int r = 0; r < 4; r++) {
      const long row = bm + wm + mi * 16 + er + r;
#pragma unroll
      for (int ni = 0; ni < 4; ni++)
        H[row * N + bn + wn + ni * 16 + ec] =
            f2h(gelu_f(acc0[mi][ni][r]) * acc1[mi][ni][r]);
    }
}

// ---------------------------------------------------------------------------
// Merged out-GEMM (shared + routed), BK=64 + swizzle, full-K (no split-K).
// y<32: shared A=Hs (K=FDIM), C=racc. y>=32: routed tile (padded positions,
// K=MDIM), C=Hout. N = DIM for both.
// ---------------------------------------------------------------------------
__global__ __launch_bounds__(256) void gemm_out2(
    const u16* __restrict__ Hs, const u16* __restrict__ swo_t,
    float* __restrict__ racc, const u16* __restrict__ Hr,
    const u16* __restrict__ ewo_t, float* __restrict__ Hout,
    const int2* __restrict__ tdesc, const int* __restrict__ n_tiles) {
  const int yb = (int)blockIdx.y;
  const u16 *A, *Bt;
  float* C;
  long bm;
  int K;
  if (yb < 32) {
    bm = (long)yb * 128;
    A = Hs;
    Bt = swo_t;
    K = FDIM;
    C = racc;
  } else {
    const int ty = yb - 32;
    if (ty >= *n_tiles) return;
    const int2 td = tdesc[ty];
    bm = td.y;
    A = Hr;
    Bt = ewo_t + (long)td.x * DIM * MDIM;
    K = MDIM;
    C = Hout;
  }
  __shared__ __align__(16) u16 As[128 * 64];  // 16 KB
  __shared__ __align__(16) u16 Bs[128 * 64];  // 16 KB
  const int tid = threadIdx.x;
  const int lane = tid & 63;
  const int wave = tid >> 6;
  const int wm = (wave >> 1) * 64;
  const int wn = (wave & 1) * 64;
  const long bn = (long)blockIdx.x * 128;

  f32x4 acc[4][4] = {};
  const int r0 = tid >> 3;
  const int cc = ((tid & 7) ^ (r0 & 7)) * 8;
  const long rowstride = 32 * (long)K;
  const u16* Ag[4];
#pragma unroll
  for (int i = 0; i < 4; i++) Ag[i] = A + (bm + r0 + i * 32) * (long)K + cc;
  const u16* Bg = Bt + (bn + r0) * (long)K + cc;
  const int fr = lane & 15;
  const int fq = lane >> 4;

  for (int k0 = 0; k0 < K; k0 += 64) {
#pragma unroll
    for (int i = 0; i < 4; i++) {
      async_copy16(Ag[i] + k0, &As[tid * 8 + i * 2048]);
      async_copy16(Bg + i * rowstride + k0, &Bs[tid * 8 + i * 2048]);
    }
    __syncthreads();
#pragma unroll
    for (int kc = 0; kc < 8; kc += 4) {
      f16x8 af[4], bq[4];
      const int q = (fq + kc) ^ (fr & 7);
#pragma unroll
      for (int i = 0; i < 4; i++) {
        af[i] = lds_frag(&As[(wm + i * 16 + fr) * 64 + q * 8]);
        bq[i] = lds_frag(&Bs[(wn + i * 16 + fr) * 64 + q * 8]);
      }
#pragma unroll
      for (int mi = 0; mi < 4; mi++)
#pragma unroll
        for (int ni = 0; ni < 4; ni++)
          acc[mi][ni] = __builtin_amdgcn_mfma_f32_16x16x32_f16(af[mi], bq[ni], acc[mi][ni], 0, 0, 0);
    }
    __syncthreads();
  }

  const int er = (lane >> 4) * 4;
  const int ec = lane & 15;
#pragma unroll
  for (int mi = 0; mi < 4; mi++)
#pragma unroll
    for (int r = 0; r < 4; r++) {
      const long row = bm + wm + mi * 16 + er + r;
#pragma unroll
      for (int ni = 0; ni < 4; ni++)
        C[row * DIM + bn + wn + ni * 16 + ec] = acc[mi][ni][r];
    }
}

// ---------------------------------------------------------------------------
// Transpose f32 [R,C] -> f16 [C,R]; dual-source variant batches over z.
// 64x64 tiles, float4 loads, LDS [64][65] (2-way = free), u16x8 stores.
// ---------------------------------------------------------------------------
__global__ __launch_bounds__(256) void transpose_cvt2(
    const float* __restrict__ s0, const float* __restrict__ s1,
    u16* __restrict__ dst, int R, int C, int zsplit) {
  __shared__ float tile[64][65];
  const int z = blockIdx.z;
  const float* src = (z < zsplit) ? s0 + (size_t)z * R * C
                                  : s1 + (size_t)(z - zsplit) * R * C;
  u16* d = dst + (size_t)z * R * C;
  const int c0 = blockIdx.x * 64, r0 = blockIdx.y * 64;
  const int tx = (threadIdx.x & 15) * 4;  // col 0,4,..,60
  const int ty = threadIdx.x >> 4;        // row 0..15
#pragma unroll
  for (int p = 0; p < 4; p++) {
    const float4 v =
        *(const float4*)(src + (size_t)(r0 + ty + p * 16) * C + c0 + tx);
    tile[ty + p * 16][tx + 0] = v.x;
    tile[ty + p * 16][tx + 1] = v.y;
    tile[ty + p * 16][tx + 2] = v.z;
    tile[ty + p * 16][tx + 3] = v.w;
  }
  __syncthreads();
  const int or8 = (threadIdx.x & 7) * 8;  // r-offset 0,8,..,56
  const int oc = threadIdx.x >> 3;        // c 0..31
#pragma unroll
  for (int p = 0; p < 2; p++) {
    const int c = oc + p * 32;
    u16x8 o;
#pragma unroll
    for (int j = 0; j < 8; j++) o[j] = f2h(tile[or8 + j][c]);
    *(u16x8*)(d + (size_t)(c0 + c) * R + r0 + or8) = o;
  }
}

// ---------------------------------------------------------------------------
// Router (+ folded x_sh f16 conversion): routed_in = rms_norm(orig,ln2s) f16;
// softmax/top2; eidx/ewt/probs. One block per token. No atomics.
// ---------------------------------------------------------------------------
__global__ __launch_bounds__(256) void router_kernel(
    const float* __restrict__ orig, const float* __restrict__ inputs,
    const float* __restrict__ pfs, const float* __restrict__ ln2s,
    const float* __restrict__ rw, u16* __restrict__ routed_in,
    u16* __restrict__ x_sh, int* __restrict__ eidx, float* __restrict__ ewt,
    float* __restrict__ probs_out) {
  const int t = blockIdx.x;
  const int tid = threadIdx.x;
  const int d = tid * 4;
  // folded cvt: inputs row -> f16
  {
    const float4 xi = *(const float4*)(inputs + (long)t * DIM + d);
    u16x4 xo = {f2h(xi.x), f2h(xi.y), f2h(xi.z), f2h(xi.w)};
    *(u16x4*)(x_sh + (long)t * DIM + d) = xo;
  }
  const float4 v = *(const float4*)(orig + (long)t * DIM + d);
  float ss = v.x * v.x + v.y * v.y + v.z * v.z + v.w * v.w;
#pragma unroll
  for (int off = 32; off > 0; off >>= 1) ss += __shfl_down(ss, off);
  __shared__ float red[4];
  __shared__ float lred[4][8];
  if ((tid & 63) == 0) red[tid >> 6] = ss;
  __syncthreads();
  const float rs = rsqrtf((red[0] + red[1] + red[2] + red[3]) * (1.0f / DIM) + 1e-6f);

  const float4 l2 = *(const float4*)(ln2s + d);
  u16x4 ro = {f2h(v.x * rs * l2.x), f2h(v.y * rs * l2.y), f2h(v.z * rs * l2.z),
              f2h(v.w * rs * l2.w)};
  *(u16x4*)(routed_in + (long)t * DIM + d) = ro;

  const float4 pf = *(const float4*)(pfs + d);
  const float c = rs * 0.03125f;  // D^-0.5
  const float g0 = v.x * c * pf.x, g1 = v.y * c * pf.y;
  const float g2 = v.z * c * pf.z, g3 = v.w * c * pf.w;
  float lg[8];
#pragma unroll
  for (int e = 0; e < 8; e++)
    lg[e] = g0 * rw[(d + 0) * 8 + e] + g1 * rw[(d + 1) * 8 + e] +
            g2 * rw[(d + 2) * 8 + e] + g3 * rw[(d + 3) * 8 + e];
#pragma unroll
  for (int e = 0; e < 8; e++)
#pragma unroll
    for (int off = 32; off > 0; off >>= 1) lg[e] += __shfl_down(lg[e], off);
  if ((tid & 63) == 0)
#pragma unroll
    for (int e = 0; e < 8; e++) lred[tid >> 6][e] = lg[e];
  __syncthreads();
  if (tid == 0) {
    float lz[8], p[8];
    float mx = -1e30f;
#pragma unroll
    for (int e = 0; e < 8; e++) {
      lz[e] = lred[0][e] + lred[1][e] + lred[2][e] + lred[3][e];
      mx = fmaxf(mx, lz[e]);
    }
    float s = 0.0f;
#pragma unroll
    for (int e = 0; e < 8; e++) {
      p[e] = expf(lz[e] - mx);
      s += p[e];
    }
    const float invs = 1.0f / s;
#pragma unroll
    for (int e = 0; e < 8; e++) p[e] *= invs;
    int i1 = 0;
    for (int e = 1; e < 8; e++)
      if (p[e] > p[i1]) i1 = e;  // strict > keeps lowest index (lax.top_k)
    int i2 = (i1 == 0) ? 1 : 0;
    for (int e = 0; e < 8; e++)
      if (e != i1 && p[e] > p[i2]) i2 = e;
    const float wsum = p[i1] + p[i2];
    eidx[2 * t] = i1;
    eidx[2 * t + 1] = i2;
    ewt[2 * t] = p[i1] / wsum;
    ewt[2 * t + 1] = p[i2] / wsum;
    float* prow = probs_out + (long)t * 8;
    for (int e = 0; e < 8; e++) prow[e] = p[e];
  }
}

// counts[e] += #assignments; LDS hist, 8 global atomics/block
__global__ __launch_bounds__(256) void bucket_count(const int* __restrict__ eidx,
                                                    int* __restrict__ counts) {
  __shared__ int lcnt[8];
  const int tid = threadIdx.x;
  if (tid < 8) lcnt[tid] = 0;
  __syncthreads();
  const int t = blockIdx.x * 256 + tid;
  atomicAdd(&lcnt[eidx[2 * t]], 1);
  atomicAdd(&lcnt[eidx[2 * t + 1]], 1);
  __syncthreads();
  if (tid < 8) atomicAdd(&counts[tid], lcnt[tid]);
}

__global__ void setup_tiles(const int* __restrict__ counts, int* __restrict__ poffset,
                            int2* __restrict__ tdesc, int* __restrict__ n_tiles) {
  if (threadIdx.x == 0 && blockIdx.x == 0) {
    int cur = 0, nt = 0;
    for (int e = 0; e < NEXP; e++) {
      poffset[e] = cur;
      const int ntile = (counts[e] + 127) >> 7;
      for (int i = 0; i < ntile; i++) {
        int2 d;
        d.x = e;
        d.y = cur + i * 128;
        tdesc[nt++] = d;
      }
      cur += ntile * 128;
    }
    n_tiles[0] = nt;
  }
}

__global__ __launch_bounds__(256) void bucket_scatter(
    const int* __restrict__ eidx, const int* __restrict__ poffset,
    int* __restrict__ cursors, int* __restrict__ ridx, int* __restrict__ pos) {
  __shared__ int lcnt[8], base[8];
  const int tid = threadIdx.x;
  if (tid < 8) lcnt[tid] = 0;
  __syncthreads();
  const int t = blockIdx.x * 256 + tid;
  const int e0 = eidx[2 * t], e1 = eidx[2 * t + 1];
  const int r0 = atomicAdd(&lcnt[e0], 1);
  const int r1 = atomicAdd(&lcnt[e1], 1);
  __syncthreads();
  if (tid < 8) base[tid] = atomicAdd(&cursors[tid], lcnt[tid]);
  __syncthreads();
  const int p0 = poffset[e0] + base[e0] + r0;
  const int p1 = poffset[e1] + base[e1] + r1;
  ridx[p0] = t;
  ridx[p1] = t;
  pos[2 * t] = p0;
  pos[2 * t + 1] = p1;
}

__global__ __launch_bounds__(256) void lb_reduce(const float* __restrict__ probs,
                                                 const int* __restrict__ counts,
                                                 float* __restrict__ out) {
  const int tid = threadIdx.x;
  float psum[8] = {};
  for (int tt = 0; tt < 16; tt++) {
    const long t = (long)tid * 16 + tt;
    const float4* pp = (const float4*)(probs + t * 8);
    const float4 p0 = pp[0], p1 = pp[1];
    psum[0] += p0.x; psum[1] += p0.y; psum[2] += p0.z; psum[3] += p0.w;
    psum[4] += p1.x; psum[5] += p1.y; psum[6] += p1.z; psum[7] += p1.w;
  }
#pragma unroll
  for (int e = 0; e < 8; e++)
#pragma unroll
    for (int off = 32; off > 0; off >>= 1) psum[e] += __shfl_down(psum[e], off);
  __shared__ float sp[4][8];
  if ((tid & 63) == 0)
#pragma unroll
    for (int e = 0; e < 8; e++) sp[tid >> 6][e] = psum[e];
  __syncthreads();
  if (tid == 0) {
    float loss = 0.0f;
#pragma unroll
    for (int e = 0; e < 8; e++) {
      const float fp = (sp[0][e] + sp[1][e] + sp[2][e] + sp[3][e]) / 4096.0f;
      const float ft = (float)counts[e] / (4096.0f * 2.0f);
      loss += ft * fp;
    }
    out[0] = 8.0f * loss;
  }
}

// ---------------------------------------------------------------------------
// Final epilogue: out = rms(shared, post1) + rms(combined routed, post2).
// Single d_out write; single (non-split) partials.
// ---------------------------------------------------------------------------
__global__ __launch_bounds__(256) void final_norm(
    const float* __restrict__ racc, const float* __restrict__ Hout,
    const int* __restrict__ pos, const float* __restrict__ ewt,
    const float* __restrict__ post1, const float* __restrict__ post2,
    float* __restrict__ out) {
  const int t = blockIdx.x;
  const int tid = threadIdx.x;
  const int d = tid * 4;
  const long base = (long)t * DIM + d;
  // shared path
  const float4 vs = *(const float4*)(racc + base);
  // routed path
  const float w0 = ewt[2 * t], w1 = ewt[2 * t + 1];
  const long p0 = pos[2 * t], p1 = pos[2 * t + 1];
  const float4 a0 = *(const float4*)(Hout + p0 * DIM + d);
  const float4 b0 = *(const float4*)(Hout + p1 * DIM + d);
  float4 vr;
  vr.x = w0 * a0.x + w1 * b0.x;
  vr.y = w0 * a0.y + w1 * b0.y;
  vr.z = w0 * a0.z + w1 * b0.z;
  vr.w = w0 * a0.w + w1 * b0.w;
  float ss = vs.x * vs.x + vs.y * vs.y + vs.z * vs.z + vs.w * vs.w;
  float sr = vr.x * vr.x + vr.y * vr.y + vr.z * vr.z + vr.w * vr.w;
#pragma unroll
  for (int off = 32; off > 0; off >>= 1) {
    ss += __shfl_down(ss, off);
    sr += __shfl_down(sr, off);
  }
  __shared__ float reds[4], redr[4];
  if ((tid & 63) == 0) {
    reds[tid >> 6] = ss;
    redr[tid >> 6] = sr;
  }
  __syncthreads();
  const float rss = rsqrtf((reds[0] + reds[1] + reds[2] + reds[3]) * (1.0f / DIM) + 1e-6f);
  const float rsr = rsqrtf((redr[0] + redr[1] + redr[2] + redr[3]) * (1.0f / DIM) + 1e-6f);
  const float4 s1 = *(const float4*)(post1 + d);
  const float4 s2 = *(const float4*)(post2 + d);
  float4 o;
  o.x = vs.x * rss * s1.x + vr.x * rsr * s2.x;
  o.y = vs.y * rss * s1.y + vr.y * rsr * s2.y;
  o.z = vs.z * rss * s1.z + vr.z * rsr * s2.z;
  o.w = vs.w * rss * s1.w + vr.w * rsr * s2.w;
  *(float4*)(out + base) = o;
}

// ---------------------------------------------------------------------------
extern "C" void kernel_launch(void* const* d_in, const int* in_sizes, int n_in,
                              void* d_out, int out_size, void* d_ws, size_t ws_size,
                              hipStream_t stream) {
  (void)in_sizes; (void)n_in; (void)out_size; (void)ws_size;
  const float* inputs   = (const float*)d_in[0];
  const float* orig     = (const float*)d_in[1];
  const float* pfs      = (const float*)d_in[2];
  const float* ln2s     = (const float*)d_in[3];
  const float* post1    = (const float*)d_in[4];
  const float* post2    = (const float*)d_in[5];
  const float* router_w = (const float*)d_in[6];
  const float* e_wi0    = (const float*)d_in[7];
  const float* e_wi1    = (const float*)d_in[8];
  const float* e_wo     = (const float*)d_in[9];
  const float* s_wi0    = (const float*)d_in[10];
  const float* s_wi1    = (const float*)d_in[11];
  const float* s_wo     = (const float*)d_in[12];

  char* ws = (char*)d_ws;
  size_t o = 0;
  auto alloc = [&](size_t bytes) -> void* {
    void* p = ws + o;
    o += (bytes + 255) & ~(size_t)255;
    return p;
  };
  u16* s_wi_t  = (u16*)alloc((size_t)2 * FDIM * DIM * 2);        // [2][F,D]
  u16* s_wo_t  = (u16*)alloc((size_t)DIM * FDIM * 2);            // [D,F]
  u16* e_wi_t  = (u16*)alloc((size_t)2 * NEXP * MDIM * DIM * 2); // [2][E,M,D]
  u16* e_wo_t  = (u16*)alloc((size_t)NEXP * DIM * MDIM * 2);     // [E,D,M]
  u16* x_sh    = (u16*)alloc((size_t)T_TOK * DIM * 2);
  u16* routed  = (u16*)alloc((size_t)T_TOK * DIM * 2);
  float* probs = (float*)alloc((size_t)T_TOK * 8 * 4);
  int* eidx    = (int*)alloc((size_t)T_TOK * 2 * 4);
  float* ewt   = (float*)alloc((size_t)T_TOK * 2 * 4);
  int* pos     = (int*)alloc((size_t)T_TOK * 2 * 4);
  int* imeta   = (int*)alloc(256);           // [0..7] counts, [8..15] cursors
  int* poffset = (int*)alloc(64);
  int* n_tiles = (int*)alloc(64);
  int2* tdesc  = (int2*)alloc(MAXTILES * 8);
  int* ridx    = (int*)alloc((size_t)HROWS * 4);
  float* racc  = (float*)alloc((size_t)T_TOK * DIM * 4);         // shared out (f32)
  u16* Hs      = (u16*)alloc((size_t)T_TOK * FDIM * 2);          // gated h (shared)
  u16* H       = (u16*)alloc((size_t)HROWS * MDIM * 2);          // gated h (routed)
  float* Hout  = (float*)alloc((size_t)HROWS * DIM * 4);         // routed out (f32)

  int* counts = imeta;
  int* cursors = imeta + 8;

  hipMemsetAsync(imeta, 0, 64, stream);
  hipMemsetAsync(ridx, 0, (size_t)HROWS * 4, stream);

  // ---- weight transposes (f32 -> f16 B^T layouts), 64x64 tiles ----
  transpose_cvt2<<<dim3(FDIM / 64, DIM / 64, 2), 256, 0, stream>>>(
      s_wi0, s_wi1, s_wi_t, DIM, FDIM, 1);
  transpose_cvt2<<<dim3(DIM / 64, FDIM / 64, 1), 256, 0, stream>>>(
      s_wo, s_wo, s_wo_t, FDIM, DIM, 1);
  transpose_cvt2<<<dim3(MDIM / 64, DIM / 64, 16), 256, 0, stream>>>(
      e_wi0, e_wi1, e_wi_t, DIM, MDIM, 8);
  transpose_cvt2<<<dim3(DIM / 64, MDIM / 64, 8), 256, 0, stream>>>(
      e_wo, e_wo, e_wo_t, MDIM, DIM, 8);

  router_kernel<<<T_TOK, 256, 0, stream>>>(orig, inputs, pfs, ln2s, router_w,
                                           routed, x_sh, eidx, ewt, probs);

  // ---- bucketing ----
  bucket_count<<<16, 256, 0, stream>>>(eidx, counts);
  setup_tiles<<<1, 64, 0, stream>>>(counts, poffset, tdesc, n_tiles);
  bucket_scatter<<<16, 256, 0, stream>>>(eidx, poffset, cursors, ridx, pos);

  // ---- merged in-GEMM (shared + routed gated) ----
  gemm_in<<<dim3(FDIM / 128, 32 + MAXTILES, 1), 256, 0, stream>>>(
      x_sh, s_wi_t, routed, e_wi_t, Hs, H, ridx, tdesc, n_tiles);

  // ---- merged out-GEMM (shared + routed, full-K) ----
  gemm_out2<<<dim3(DIM / 128, 32 + MAXTILES, 1), 256, 0, stream>>>(
      Hs, s_wo_t, racc, H, e_wo_t, Hout, tdesc, n_tiles);

  // ---- fused final norm + combine ----
  final_norm<<<T_TOK, 256, 0, stream>>>(racc, Hout, pos, ewt, post1, post2,
                                        (float*)d_out);

  lb_reduce<<<1, 256, 0, stream>>>(probs, counts, (float*)d_out + (size_t)T_TOK * DIM);
}

// Round 5
// 418.496 us; speedup vs baseline: 1.1254x; 1.0120x over previous
//
#include <hip/hip_runtime.h>
#include <stdint.h>

// ---------------------------------------------------------------------------
// Gemma4 MoE block on gfx950. FP16 MFMA (16x16x32) GEMMs, f32 accumulation.
// R2: sparse top-2 routed experts (tile-padded bucketing + grouped GEMMs).
// R4: gated dual-GEMM, 256 thr, dual acc, BK=64, XOR source swizzle (0 bank
//     conflicts). R6: dispatch merging (one in-GEMM, one out-GEMM launch).
// R7/R8: counted-vmcnt pipeline attempts REGRESSED (m232 failure mode).
// R9: gemm_out2 split-K removed. R10: 64x64 vectorized transpose_cvt.
// R11: launch-count 13 -> 6. transpose_all (one dispatch, 7680 exact tiles);
//      wave-per-token router (no barriers); single-block bucket_all
//      (count+tiles+scatter+pad, no memsets); lb_reduce folded into
//      final_norm. GEMM cores untouched.
// ---------------------------------------------------------------------------

typedef unsigned short u16;
typedef u16 u16x4 __attribute__((ext_vector_type(4)));
typedef u16 u16x8 __attribute__((ext_vector_type(8)));
typedef _Float16 f16x8 __attribute__((ext_vector_type(8)));
typedef float f32x4 __attribute__((ext_vector_type(4)));
typedef __attribute__((address_space(1))) void* as1_vp;
typedef __attribute__((address_space(3))) void* as3_vp;

#define T_TOK 4096
#define DIM   1024
#define FDIM  2048
#define MDIM  1024
#define NEXP  8
#define MAXTILES 72            // sum ceil(cnt_e/128) <= 64 + 7, padded
#define HROWS (MAXTILES * 128) // 9216 padded assignment rows

__device__ __forceinline__ u16 f2h(float f) {
  _Float16 h = (_Float16)f;
  return __builtin_bit_cast(u16, h);
}
// tanh-approx gelu rewritten exactly as x*sigmoid(2y): cheap __expf + div
__device__ __forceinline__ float gelu_f(float x) {
  const float y2 = x * (1.5957691216f + 0.0713548163f * x * x);
  return x / (1.0f + __expf(-y2));
}
__device__ __forceinline__ void async_copy16(const void* g, void* l) {
  __builtin_amdgcn_global_load_lds((as1_vp)(uintptr_t)g,
                                   (as3_vp)(uint32_t)(uintptr_t)l, 16, 0, 0);
}
__device__ __forceinline__ f16x8 lds_frag(const u16* p) {
  return __builtin_bit_cast(f16x8, *(const u16x8*)p);
}
__device__ __forceinline__ u16x8 pack8(float4 a, float4 b) {
  u16x8 o;
  o[0] = f2h(a.x); o[1] = f2h(a.y); o[2] = f2h(a.z); o[3] = f2h(a.w);
  o[4] = f2h(b.x); o[5] = f2h(b.y); o[6] = f2h(b.z); o[7] = f2h(b.w);
  return o;
}

// ---------------------------------------------------------------------------
// Merged gated dual-GEMM (shared + routed in ONE dispatch).
// H = gelu(A@B0) * (A@B1), f16. 256 thr / 4 waves (2x2 of 64x64), dual acc
// per wave (in-register gelu*mul). BK=64, 48 KB LDS, XOR source swizzle.
// blockIdx.y < 32: shared (A=x_sh, N=FDIM, all 16 x-blocks).
// blockIdx.y >= 32: routed tile (gather rows via ridx, N=MDIM, x < 8).
// K = DIM = 1024 for both.
// ---------------------------------------------------------------------------
__global__ __launch_bounds__(256, 2) void gemm_in(
    const u16* __restrict__ xs, const u16* __restrict__ swi_t,
    const u16* __restrict__ routed, const u16* __restrict__ ewi_t,
    u16* __restrict__ Hs, u16* __restrict__ Hr,
    const int* __restrict__ ridx, const int2* __restrict__ tdesc,
    const int* __restrict__ n_tiles) {
  const int yb = (int)blockIdx.y;
  const u16 *A, *B0t, *B1t;
  u16* H;
  int N;
  long bm;
  bool gather;
  if (yb < 32) {
    bm = (long)yb * 128;
    A = xs;
    B0t = swi_t;
    B1t = swi_t + (size_t)FDIM * DIM;
    H = Hs;
    N = FDIM;
    gather = false;
  } else {
    const int ty = yb - 32;
    if (ty >= *n_tiles) return;
    if ((int)blockIdx.x >= MDIM / 128) return;
    const int2 td = tdesc[ty];
    bm = td.y;
    A = routed;
    B0t = ewi_t + (long)td.x * MDIM * DIM;
    B1t = ewi_t + (size_t)NEXP * MDIM * DIM + (long)td.x * MDIM * DIM;
    H = Hr;
    N = MDIM;
    gather = true;
  }
  __shared__ __align__(16) u16 As[128 * 64];   // 16 KB
  __shared__ __align__(16) u16 Bs0[128 * 64];  // 16 KB
  __shared__ __align__(16) u16 Bs1[128 * 64];  // 16 KB
  const int tid = threadIdx.x;
  const int lane = tid & 63;
  const int wave = tid >> 6;
  const int wm = (wave >> 1) * 64;
  const int wn = (wave & 1) * 64;
  const long bn = (long)blockIdx.x * 128;

  f32x4 acc0[4][4] = {}, acc1[4][4] = {};

  // Staging: slot s = (row, swizzled chunk); lane-linear LDS dest, swizzle on
  // global source index (validated R5: SQ_LDS_BANK_CONFLICT = 0).
  const int r0 = tid >> 3;
  const int cc = ((tid & 7) ^ (r0 & 7)) * 8;
  const long rowstride = 32 * (long)DIM;
  const u16* Ag[4];
  if (gather) {
#pragma unroll
    for (int i = 0; i < 4; i++) Ag[i] = A + (long)ridx[bm + r0 + i * 32] * DIM + cc;
  } else {
#pragma unroll
    for (int i = 0; i < 4; i++) Ag[i] = A + (bm + r0 + i * 32) * (long)DIM + cc;
  }
  const u16* B0g = B0t + (bn + r0) * (long)DIM + cc;
  const u16* B1g = B1t + (bn + r0) * (long)DIM + cc;
  const int fr = lane & 15;
  const int fq = lane >> 4;

  for (int k0 = 0; k0 < DIM; k0 += 64) {
#pragma unroll
    for (int i = 0; i < 4; i++) {
      async_copy16(Ag[i] + k0, &As[tid * 8 + i * 2048]);
      async_copy16(B0g + i * rowstride + k0, &Bs0[tid * 8 + i * 2048]);
      async_copy16(B1g + i * rowstride + k0, &Bs1[tid * 8 + i * 2048]);
    }
    __syncthreads();
#pragma unroll
    for (int kc = 0; kc < 8; kc += 4) {
      f16x8 af[4], b0[4], b1[4];
      const int q = (fq + kc) ^ (fr & 7);
#pragma unroll
      for (int i = 0; i < 4; i++) {
        af[i] = lds_frag(&As[(wm + i * 16 + fr) * 64 + q * 8]);
        b0[i] = lds_frag(&Bs0[(wn + i * 16 + fr) * 64 + q * 8]);
        b1[i] = lds_frag(&Bs1[(wn + i * 16 + fr) * 64 + q * 8]);
      }
#pragma unroll
      for (int mi = 0; mi < 4; mi++)
#pragma unroll
        for (int ni = 0; ni < 4; ni++) {
          acc0[mi][ni] = __builtin_amdgcn_mfma_f32_16x16x32_f16(af[mi], b0[ni], acc0[mi][ni], 0, 0, 0);
          acc1[mi][ni] = __builtin_amdgcn_mfma_f32_16x16x32_f16(af[mi], b1[ni], acc1[mi][ni], 0, 0, 0);
        }
    }
    __syncthreads();
  }

  const int er = (lane >> 4) * 4;  // C/D: col=lane&15, row=(lane>>4)*4+reg
  const int ec = lane & 15;
#pragma unroll
  for (int mi = 0; mi < 4; mi++)
#pragma unroll
    for (int r = 0; r < 4; r++) {
      const long row = bm + wm + mi * 16 + er + r;
#pragma unroll
      for (int ni = 0; ni < 4; ni++)
        H[row * N + bn + wn + ni * 16 + ec] =
            f2h(gelu_f(acc0[mi][ni][r]) * acc1[mi][ni][r]);
    }
}

// ---------------------------------------------------------------------------
// Merged out-GEMM (shared + routed), BK=64 + swizzle, full-K (no split-K).
// y<32: shared A=Hs (K=FDIM), C=racc. y>=32: routed tile (padded positions,
// K=MDIM), C=Hout. N = DIM for both.
// ---------------------------------------------------------------------------
__global__ __launch_bounds__(256) void gemm_out2(
    const u16* __restrict__ Hs, const u16* __restrict__ swo_t,
    float* __restrict__ racc, const u16* __restrict__ Hr,
    const u16* __restrict__ ewo_t, float* __restrict__ Hout,
    const int2* __restrict__ tdesc, const int* __restrict__ n_tiles) {
  const int yb = (int)blockIdx.y;
  const u16 *A, *Bt;
  float* C;
  long bm;
  int K;
  if (yb < 32) {
    bm = (long)yb * 128;
    A = Hs;
    Bt = swo_t;
    K = FDIM;
    C = racc;
  } else {
    const int ty = yb - 32;
    if (ty >= *n_tiles) return;
    const int2 td = tdesc[ty];
    bm = td.y;
    A = Hr;
    Bt = ewo_t + (long)td.x * DIM * MDIM;
    K = MDIM;
    C = Hout;
  }
  __shared__ __align__(16) u16 As[128 * 64];  // 16 KB
  __shared__ __align__(16) u16 Bs[128 * 64];  // 16 KB
  const int tid = threadIdx.x;
  const int lane = tid & 63;
  const int wave = tid >> 6;
  const int wm = (wave >> 1) * 64;
  const int wn = (wave & 1) * 64;
  const long bn = (long)blockIdx.x * 128;

  f32x4 acc[4][4] = {};
  const int r0 = tid >> 3;
  const int cc = ((tid & 7) ^ (r0 & 7)) * 8;
  const long rowstride = 32 * (long)K;
  const u16* Ag[4];
#pragma unroll
  for (int i = 0; i < 4; i++) Ag[i] = A + (bm + r0 + i * 32) * (long)K + cc;
  const u16* Bg = Bt + (bn + r0) * (long)K + cc;
  const int fr = lane & 15;
  const int fq = lane >> 4;

  for (int k0 = 0; k0 < K; k0 += 64) {
#pragma unroll
    for (int i = 0; i < 4; i++) {
      async_copy16(Ag[i] + k0, &As[tid * 8 + i * 2048]);
      async_copy16(Bg + i * rowstride + k0, &Bs[tid * 8 + i * 2048]);
    }
    __syncthreads();
#pragma unroll
    for (int kc = 0; kc < 8; kc += 4) {
      f16x8 af[4], bq[4];
      const int q = (fq + kc) ^ (fr & 7);
#pragma unroll
      for (int i = 0; i < 4; i++) {
        af[i] = lds_frag(&As[(wm + i * 16 + fr) * 64 + q * 8]);
        bq[i] = lds_frag(&Bs[(wn + i * 16 + fr) * 64 + q * 8]);
      }
#pragma unroll
      for (int mi = 0; mi < 4; mi++)
#pragma unroll
        for (int ni = 0; ni < 4; ni++)
          acc[mi][ni] = __builtin_amdgcn_mfma_f32_16x16x32_f16(af[mi], bq[ni], acc[mi][ni], 0, 0, 0);
    }
    __syncthreads();
  }

  const int er = (lane >> 4) * 4;
  const int ec = lane & 15;
#pragma unroll
  for (int mi = 0; mi < 4; mi++)
#pragma unroll
    for (int r = 0; r < 4; r++) {
      const long row = bm + wm + mi * 16 + er + r;
#pragma unroll
      for (int ni = 0; ni < 4; ni++)
        C[row * DIM + bn + wn + ni * 16 + ec] = acc[mi][ni][r];
    }
}

// ---------------------------------------------------------------------------
// ALL weight transposes in ONE dispatch. f32 [R,C] -> f16 [C,R].
// 1-D grid of exactly 7680 64x64 tiles over 27 slices:
//   [0,1024):   s_wi0/s_wi1 -> s_wi_t   (R=1024, C=2048; 512 tiles/slice)
//   [1024,1536): s_wo -> s_wo_t        (R=2048, C=1024; 512 tiles)
//   [1536,5632): e_wi0|e_wi1 -> e_wi_t (R=1024, C=1024; 256 tiles/slice x16)
//   [5632,7680): e_wo -> e_wo_t        (R=1024, C=1024; 256 tiles/slice x8)
// Body: float4 loads, LDS [64][65] (2-way = free), u16x8 16B stores.
// ---------------------------------------------------------------------------
__global__ __launch_bounds__(256) void transpose_all(
    const float* __restrict__ s_wi0, const float* __restrict__ s_wi1,
    const float* __restrict__ s_wo, const float* __restrict__ e_wi0,
    const float* __restrict__ e_wi1, const float* __restrict__ e_wo,
    u16* __restrict__ s_wi_t, u16* __restrict__ s_wo_t,
    u16* __restrict__ e_wi_t, u16* __restrict__ e_wo_t) {
  const int b = (int)blockIdx.x;
  const float* src;
  u16* dst;
  int R, C, tile;
  if (b < 1024) {
    const int z = b >> 9;
    tile = b & 511;
    src = z ? s_wi1 : s_wi0;
    dst = s_wi_t + (size_t)z * FDIM * DIM;
    R = DIM; C = FDIM;
  } else if (b < 1536) {
    tile = b - 1024;
    src = s_wo;
    dst = s_wo_t;
    R = FDIM; C = DIM;
  } else if (b < 5632) {
    const int z = (b - 1536) >> 8;
    tile = b & 255;
    src = (z < 8) ? e_wi0 + (size_t)z * DIM * MDIM
                  : e_wi1 + (size_t)(z - 8) * DIM * MDIM;
    dst = e_wi_t + (size_t)z * MDIM * DIM;
    R = DIM; C = MDIM;
  } else {
    const int z = (b - 5632) >> 8;
    tile = b & 255;
    src = e_wo + (size_t)z * MDIM * DIM;
    dst = e_wo_t + (size_t)z * DIM * MDIM;
    R = MDIM; C = DIM;
  }
  const int ctiles = C >> 6;
  const int c0 = (tile % ctiles) * 64, r0 = (tile / ctiles) * 64;

  __shared__ float tl[64][65];
  const int tx = (threadIdx.x & 15) * 4;  // col 0,4,..,60
  const int ty = threadIdx.x >> 4;        // row 0..15
#pragma unroll
  for (int p = 0; p < 4; p++) {
    const float4 v =
        *(const float4*)(src + (size_t)(r0 + ty + p * 16) * C + c0 + tx);
    tl[ty + p * 16][tx + 0] = v.x;
    tl[ty + p * 16][tx + 1] = v.y;
    tl[ty + p * 16][tx + 2] = v.z;
    tl[ty + p * 16][tx + 3] = v.w;
  }
  __syncthreads();
  const int or8 = (threadIdx.x & 7) * 8;  // r-offset 0,8,..,56
  const int oc = threadIdx.x >> 3;        // c 0..31
#pragma unroll
  for (int p = 0; p < 2; p++) {
    const int c = oc + p * 32;
    u16x8 o;
#pragma unroll
    for (int j = 0; j < 8; j++) o[j] = f2h(tl[or8 + j][c]);
    *(u16x8*)(dst + (size_t)(c0 + c) * R + r0 + or8) = o;
  }
}

// ---------------------------------------------------------------------------
// Router, wave-per-token (4 tokens / 256-thr block, no barriers, no LDS).
// Lane l owns dims [16l, 16l+16). Folded x_sh f16 conversion.
// routed_in = rms_norm(orig,ln2s) f16; softmax/top2 -> eidx/ewt/probs.
// ---------------------------------------------------------------------------
__global__ __launch_bounds__(256) void router_kernel(
    const float* __restrict__ orig, const float* __restrict__ inputs,
    const float* __restrict__ pfs, const float* __restrict__ ln2s,
    const float* __restrict__ rw, u16* __restrict__ routed_in,
    u16* __restrict__ x_sh, int* __restrict__ eidx, float* __restrict__ ewt,
    float* __restrict__ probs_out) {
  const int wv = threadIdx.x >> 6;
  const int lane = threadIdx.x & 63;
  const int t = blockIdx.x * 4 + wv;
  const int d0 = lane * 16;
  const size_t base = (size_t)t * DIM + d0;

  const float4 v0 = *(const float4*)(orig + base);
  const float4 v1 = *(const float4*)(orig + base + 4);
  const float4 v2 = *(const float4*)(orig + base + 8);
  const float4 v3 = *(const float4*)(orig + base + 12);
  {
    const float4 x0 = *(const float4*)(inputs + base);
    const float4 x1 = *(const float4*)(inputs + base + 4);
    const float4 x2 = *(const float4*)(inputs + base + 8);
    const float4 x3 = *(const float4*)(inputs + base + 12);
    *(u16x8*)(x_sh + base) = pack8(x0, x1);
    *(u16x8*)(x_sh + base + 8) = pack8(x2, x3);
  }
  float ss = v0.x * v0.x + v0.y * v0.y + v0.z * v0.z + v0.w * v0.w +
             v1.x * v1.x + v1.y * v1.y + v1.z * v1.z + v1.w * v1.w +
             v2.x * v2.x + v2.y * v2.y + v2.z * v2.z + v2.w * v2.w +
             v3.x * v3.x + v3.y * v3.y + v3.z * v3.z + v3.w * v3.w;
#pragma unroll
  for (int off = 32; off > 0; off >>= 1) ss += __shfl_down(ss, off);
  ss = __shfl(ss, 0);
  const float rs = rsqrtf(ss * (1.0f / DIM) + 1e-6f);

  {
    const float4 l0 = *(const float4*)(ln2s + d0);
    const float4 l1 = *(const float4*)(ln2s + d0 + 4);
    const float4 l2 = *(const float4*)(ln2s + d0 + 8);
    const float4 l3 = *(const float4*)(ln2s + d0 + 12);
    float4 r0c, r1c, r2c, r3c;
    r0c.x = v0.x * rs * l0.x; r0c.y = v0.y * rs * l0.y;
    r0c.z = v0.z * rs * l0.z; r0c.w = v0.w * rs * l0.w;
    r1c.x = v1.x * rs * l1.x; r1c.y = v1.y * rs * l1.y;
    r1c.z = v1.z * rs * l1.z; r1c.w = v1.w * rs * l1.w;
    r2c.x = v2.x * rs * l2.x; r2c.y = v2.y * rs * l2.y;
    r2c.z = v2.z * rs * l2.z; r2c.w = v2.w * rs * l2.w;
    r3c.x = v3.x * rs * l3.x; r3c.y = v3.y * rs * l3.y;
    r3c.z = v3.z * rs * l3.z; r3c.w = v3.w * rs * l3.w;
    *(u16x8*)(routed_in + base) = pack8(r0c, r1c);
    *(u16x8*)(routed_in + base + 8) = pack8(r2c, r3c);
  }

  const float4 p0 = *(const float4*)(pfs + d0);
  const float4 p1 = *(const float4*)(pfs + d0 + 4);
  const float4 p2 = *(const float4*)(pfs + d0 + 8);
  const float4 p3 = *(const float4*)(pfs + d0 + 12);
  const float c = rs * 0.03125f;  // D^-0.5
  const float g[16] = {v0.x * c * p0.x, v0.y * c * p0.y, v0.z * c * p0.z, v0.w * c * p0.w,
                       v1.x * c * p1.x, v1.y * c * p1.y, v1.z * c * p1.z, v1.w * c * p1.w,
                       v2.x * c * p2.x, v2.y * c * p2.y, v2.z * c * p2.z, v2.w * c * p2.w,
                       v3.x * c * p3.x, v3.y * c * p3.y, v3.z * c * p3.z, v3.w * c * p3.w};
  float lg[8] = {};
#pragma unroll
  for (int j = 0; j < 16; j++) {
    const float4 ra = *(const float4*)(rw + (size_t)(d0 + j) * 8);
    const float4 rb = *(const float4*)(rw + (size_t)(d0 + j) * 8 + 4);
    lg[0] += g[j] * ra.x; lg[1] += g[j] * ra.y;
    lg[2] += g[j] * ra.z; lg[3] += g[j] * ra.w;
    lg[4] += g[j] * rb.x; lg[5] += g[j] * rb.y;
    lg[6] += g[j] * rb.z; lg[7] += g[j] * rb.w;
  }
#pragma unroll
  for (int e = 0; e < 8; e++)
#pragma unroll
    for (int off = 32; off > 0; off >>= 1) lg[e] += __shfl_down(lg[e], off);

  if (lane == 0) {
    float p[8];
    float mx = -1e30f;
#pragma unroll
    for (int e = 0; e < 8; e++) mx = fmaxf(mx, lg[e]);
    float s = 0.0f;
#pragma unroll
    for (int e = 0; e < 8; e++) {
      p[e] = expf(lg[e] - mx);
      s += p[e];
    }
    const float invs = 1.0f / s;
#pragma unroll
    for (int e = 0; e < 8; e++) p[e] *= invs;
    int i1 = 0;
    for (int e = 1; e < 8; e++)
      if (p[e] > p[i1]) i1 = e;  // strict > keeps lowest index (lax.top_k)
    int i2 = (i1 == 0) ? 1 : 0;
    for (int e = 0; e < 8; e++)
      if (e != i1 && p[e] > p[i2]) i2 = e;
    const float wsum = p[i1] + p[i2];
    eidx[2 * t] = i1;
    eidx[2 * t + 1] = i2;
    ewt[2 * t] = p[i1] / wsum;
    ewt[2 * t + 1] = p[i2] / wsum;
    float* prow = probs_out + (size_t)t * 8;
    for (int e = 0; e < 8; e++) prow[e] = p[e];
  }
}

// ---------------------------------------------------------------------------
// Single-block bucketing: histogram + tile descriptors + scatter + pad fill.
// Replaces bucket_count + setup_tiles + bucket_scatter + both memsets.
// ---------------------------------------------------------------------------
__global__ __launch_bounds__(512) void bucket_all(
    const int* __restrict__ eidx, int* __restrict__ counts_g,
    int2* __restrict__ tdesc, int* __restrict__ n_tiles,
    int* __restrict__ ridx, int* __restrict__ pos) {
  __shared__ int cnt[8], off[8], cursor[8];
  const int tid = threadIdx.x;
  if (tid < 8) {
    cnt[tid] = 0;
    cursor[tid] = 0;
  }
  __syncthreads();
  for (int i = tid; i < 2 * T_TOK; i += 512) atomicAdd(&cnt[eidx[i]], 1);
  __syncthreads();
  if (tid == 0) {
    int cur = 0, nt = 0;
    for (int e = 0; e < NEXP; e++) {
      off[e] = cur;
      counts_g[e] = cnt[e];
      const int ntile = (cnt[e] + 127) >> 7;
      for (int i = 0; i < ntile; i++) {
        int2 d;
        d.x = e;
        d.y = cur + i * 128;
        tdesc[nt++] = d;
      }
      cur += ntile * 128;
    }
    n_tiles[0] = nt;
  }
  __syncthreads();
  for (int i = tid; i < 2 * T_TOK; i += 512) {
    const int e = eidx[i];
    const int r = atomicAdd(&cursor[e], 1);
    const int p = off[e] + r;
    ridx[p] = i >> 1;
    pos[i] = p;
  }
  __syncthreads();
  // pad fill: rows [off+cnt, off+ntile*128) point at token 0 (safe gather)
#pragma unroll
  for (int e = 0; e < NEXP; e++) {
    const int s = off[e] + cnt[e];
    const int en = off[e] + (((cnt[e] + 127) >> 7) << 7);
    for (int i = s + tid; i < en; i += 512) ridx[i] = 0;
  }
}

// ---------------------------------------------------------------------------
// Final epilogue: out = rms(shared, post1) + rms(combined routed, post2).
// Block T_TOK additionally computes the load-balance loss (folded lb_reduce).
// ---------------------------------------------------------------------------
__global__ __launch_bounds__(256) void final_norm(
    const float* __restrict__ racc, const float* __restrict__ Hout,
    const int* __restrict__ pos, const float* __restrict__ ewt,
    const float* __restrict__ post1, const float* __restrict__ post2,
    float* __restrict__ out, const float* __restrict__ probs,
    const int* __restrict__ counts) {
  const int tid = threadIdx.x;
  if (blockIdx.x == T_TOK) {  // folded lb_reduce
    float psum[8] = {};
    for (int tt = 0; tt < 16; tt++) {
      const long t = (long)tid * 16 + tt;
      const float4* pp = (const float4*)(probs + t * 8);
      const float4 p0 = pp[0], p1 = pp[1];
      psum[0] += p0.x; psum[1] += p0.y; psum[2] += p0.z; psum[3] += p0.w;
      psum[4] += p1.x; psum[5] += p1.y; psum[6] += p1.z; psum[7] += p1.w;
    }
#pragma unroll
    for (int e = 0; e < 8; e++)
#pragma unroll
      for (int off = 32; off > 0; off >>= 1) psum[e] += __shfl_down(psum[e], off);
    __shared__ float sp[4][8];
    if ((tid & 63) == 0)
#pragma unroll
      for (int e = 0; e < 8; e++) sp[tid >> 6][e] = psum[e];
    __syncthreads();
    if (tid == 0) {
      float loss = 0.0f;
#pragma unroll
      for (int e = 0; e < 8; e++) {
        const float fp = (sp[0][e] + sp[1][e] + sp[2][e] + sp[3][e]) / 4096.0f;
        const float ft = (float)counts[e] / (4096.0f * 2.0f);
        loss += ft * fp;
      }
      out[(size_t)T_TOK * DIM] = 8.0f * loss;
    }
    return;
  }
  const int t = blockIdx.x;
  const int d = tid * 4;
  const long base = (long)t * DIM + d;
  // shared path
  const float4 vs = *(const float4*)(racc + base);
  // routed path
  const float w0 = ewt[2 * t], w1 = ewt[2 * t + 1];
  const long p0 = pos[2 * t], p1 = pos[2 * t + 1];
  const float4 a0 = *(const float4*)(Hout + p0 * DIM + d);
  const float4 b0 = *(const float4*)(Hout + p1 * DIM + d);
  float4 vr;
  vr.x = w0 * a0.x + w1 * b0.x;
  vr.y = w0 * a0.y + w1 * b0.y;
  vr.z = w0 * a0.z + w1 * b0.z;
  vr.w = w0 * a0.w + w1 * b0.w;
  float ss = vs.x * vs.x + vs.y * vs.y + vs.z * vs.z + vs.w * vs.w;
  float sr = vr.x * vr.x + vr.y * vr.y + vr.z * vr.z + vr.w * vr.w;
#pragma unroll
  for (int off = 32; off > 0; off >>= 1) {
    ss += __shfl_down(ss, off);
    sr += __shfl_down(sr, off);
  }
  __shared__ float reds[4], redr[4];
  if ((tid & 63) == 0) {
    reds[tid >> 6] = ss;
    redr[tid >> 6] = sr;
  }
  __syncthreads();
  const float rss = rsqrtf((reds[0] + reds[1] + reds[2] + reds[3]) * (1.0f / DIM) + 1e-6f);
  const float rsr = rsqrtf((redr[0] + redr[1] + redr[2] + redr[3]) * (1.0f / DIM) + 1e-6f);
  const float4 s1 = *(const float4*)(post1 + d);
  const float4 s2 = *(const float4*)(post2 + d);
  float4 o;
  o.x = vs.x * rss * s1.x + vr.x * rsr * s2.x;
  o.y = vs.y * rss * s1.y + vr.y * rsr * s2.y;
  o.z = vs.z * rss * s1.z + vr.z * rsr * s2.z;
  o.w = vs.w * rss * s1.w + vr.w * rsr * s2.w;
  *(float4*)(out + base) = o;
}

// ---------------------------------------------------------------------------
extern "C" void kernel_launch(void* const* d_in, const int* in_sizes, int n_in,
                              void* d_out, int out_size, void* d_ws, size_t ws_size,
                              hipStream_t stream) {
  (void)in_sizes; (void)n_in; (void)out_size; (void)ws_size;
  const float* inputs   = (const float*)d_in[0];
  const float* orig     = (const float*)d_in[1];
  const float* pfs      = (const float*)d_in[2];
  const float* ln2s     = (const float*)d_in[3];
  const float* post1    = (const float*)d_in[4];
  const float* post2    = (const float*)d_in[5];
  const float* router_w = (const float*)d_in[6];
  const float* e_wi0    = (const float*)d_in[7];
  const float* e_wi1    = (const float*)d_in[8];
  const float* e_wo     = (const float*)d_in[9];
  const float* s_wi0    = (const float*)d_in[10];
  const float* s_wi1    = (const float*)d_in[11];
  const float* s_wo     = (const float*)d_in[12];

  char* ws = (char*)d_ws;
  size_t o = 0;
  auto alloc = [&](size_t bytes) -> void* {
    void* p = ws + o;
    o += (bytes + 255) & ~(size_t)255;
    return p;
  };
  u16* s_wi_t  = (u16*)alloc((size_t)2 * FDIM * DIM * 2);        // [2][F,D]
  u16* s_wo_t  = (u16*)alloc((size_t)DIM * FDIM * 2);            // [D,F]
  u16* e_wi_t  = (u16*)alloc((size_t)2 * NEXP * MDIM * DIM * 2); // [2][E,M,D]
  u16* e_wo_t  = (u16*)alloc((size_t)NEXP * DIM * MDIM * 2);     // [E,D,M]
  u16* x_sh    = (u16*)alloc((size_t)T_TOK * DIM * 2);
  u16* routed  = (u16*)alloc((size_t)T_TOK * DIM * 2);
  float* probs = (float*)alloc((size_t)T_TOK * 8 * 4);
  int* eidx    = (int*)alloc((size_t)T_TOK * 2 * 4);
  float* ewt   = (float*)alloc((size_t)T_TOK * 2 * 4);
  int* pos     = (int*)alloc((size_t)T_TOK * 2 * 4);
  int* imeta   = (int*)alloc(256);           // [0..7] counts
  int* n_tiles = (int*)alloc(64);
  int2* tdesc  = (int2*)alloc(MAXTILES * 8);
  int* ridx    = (int*)alloc((size_t)HROWS * 4);
  float* racc  = (float*)alloc((size_t)T_TOK * DIM * 4);         // shared out (f32)
  u16* Hs      = (u16*)alloc((size_t)T_TOK * FDIM * 2);          // gated h (shared)
  u16* H       = (u16*)alloc((size_t)HROWS * MDIM * 2);          // gated h (routed)
  float* Hout  = (float*)alloc((size_t)HROWS * DIM * 4);         // routed out (f32)

  int* counts = imeta;

  // ---- all weight transposes, ONE dispatch ----
  transpose_all<<<7680, 256, 0, stream>>>(s_wi0, s_wi1, s_wo, e_wi0, e_wi1,
                                          e_wo, s_wi_t, s_wo_t, e_wi_t, e_wo_t);

  // ---- router (wave per token) ----
  router_kernel<<<T_TOK / 4, 256, 0, stream>>>(orig, inputs, pfs, ln2s,
                                               router_w, routed, x_sh, eidx,
                                               ewt, probs);

  // ---- bucketing, ONE single-block dispatch (no memsets needed) ----
  bucket_all<<<1, 512, 0, stream>>>(eidx, counts, tdesc, n_tiles, ridx, pos);

  // ---- merged in-GEMM (shared + routed gated) ----
  gemm_in<<<dim3(FDIM / 128, 32 + MAXTILES, 1), 256, 0, stream>>>(
      x_sh, s_wi_t, routed, e_wi_t, Hs, H, ridx, tdesc, n_tiles);

  // ---- merged out-GEMM (shared + routed, full-K) ----
  gemm_out2<<<dim3(DIM / 128, 32 + MAXTILES, 1), 256, 0, stream>>>(
      Hs, s_wo_t, racc, H, e_wo_t, Hout, tdesc, n_tiles);

  // ---- fused final norm + combine (+ folded lb loss in block T_TOK) ----
  final_norm<<<T_TOK + 1, 256, 0, stream>>>(racc, Hout, pos, ewt, post1, post2,
                                            (float*)d_out, probs, counts);
}